// Round 2
// baseline (9429.691 us; speedup 1.0000x reference)
//
#include <hip/hip_runtime.h>
#include <hip/hip_bf16.h>
#include <cmath>

typedef __hip_bfloat16 bf16;

#define B_   32
#define T_   252
#define F_   8
#define D_   512
#define NH_  8
#define DH_  64
#define DI_  1024
#define DHI_ 128
#define FF_  682
#define FF2_ 1364
#define BT_  (B_*T_)
#define EPS_ 1e-5f

__device__ __forceinline__ float b2f(bf16 v){ return __bfloat162float(v); }
__device__ __forceinline__ float siluf(float x){ return x/(1.f+expf(-x)); }
__device__ __forceinline__ float geluf(float x){
  float x3 = x*x*x;
  return 0.5f*x*(1.f+tanhf(0.7978845608028654f*(x+0.044715f*x3)));
}
// dtype-robust input load: harness may store float inputs as bf16 or fp32
__device__ __forceinline__ float ldin(const void* p, long i, int isbf){
  return isbf ? __bfloat162float(((const bf16*)p)[i]) : ((const float*)p)[i];
}

__global__ void detect_dtype(const unsigned* __restrict__ probe, int* __restrict__ flag)
{
  if (threadIdx.x == 0) *flag = (*probe == 0x3F803F80u) ? 1 : 0;
}

// ---------------- input projection + layernorm ----------------
__global__ __launch_bounds__(256) void ln_proj(
    const void* __restrict__ x, const void* __restrict__ w,
    const void* __restrict__ bb, const void* __restrict__ s,
    const void* __restrict__ b, float* __restrict__ out,
    const int* __restrict__ dflag)
{
  const int isbf = *dflag;
  const int r = blockIdx.x;
  const int tid = threadIdx.x;
  float xr[8];
#pragma unroll
  for (int f = 0; f < 8; f++) xr[f] = ldin(x, (long)r*8+f, isbf);
  float vv[2];
#pragma unroll
  for (int i2 = 0; i2 < 2; i2++) {
    const int j = tid + i2*256;
    float a = ldin(bb, j, isbf);
#pragma unroll
    for (int f = 0; f < 8; f++) a += xr[f]*ldin(w, f*512+j, isbf);
    vv[i2] = a;
  }
  __shared__ float r1[256], r2[256];
  r1[tid] = vv[0]+vv[1]; r2[tid] = vv[0]*vv[0]+vv[1]*vv[1];
  __syncthreads();
  for (int o = 128; o > 0; o >>= 1) {
    if (tid < o) { r1[tid]+=r1[tid+o]; r2[tid]+=r2[tid+o]; }
    __syncthreads();
  }
  const float mu = r1[0]*(1.f/512.f);
  const float var = r2[0]*(1.f/512.f)-mu*mu;
  const float rstd = rsqrtf(var+EPS_);
  float* orow = out + (long)r*512;
#pragma unroll
  for (int i2 = 0; i2 < 2; i2++) {
    const int j = tid + i2*256;
    orow[j] = (vv[i2]-mu)*rstd*ldin(s, j, isbf) + ldin(b, j, isbf);
  }
}

// ---------------- layernorm over 512-elem rows ----------------
__global__ __launch_bounds__(256) void ln_rows(
    const float* __restrict__ in, long rowStride,
    const void* __restrict__ s, long offS,
    const void* __restrict__ b, long offB,
    float* __restrict__ out, const int* __restrict__ dflag)
{
  const int isbf = *dflag;
  const long r = blockIdx.x;
  const int tid = threadIdx.x;
  const float* xr = in + r*rowStride;
  const float v0 = xr[tid], v1 = xr[tid+256];
  __shared__ float r1[256], r2[256];
  r1[tid] = v0+v1; r2[tid] = v0*v0+v1*v1;
  __syncthreads();
  for (int o = 128; o > 0; o >>= 1) {
    if (tid < o) { r1[tid]+=r1[tid+o]; r2[tid]+=r2[tid+o]; }
    __syncthreads();
  }
  const float mu = r1[0]*(1.f/512.f);
  const float var = r2[0]*(1.f/512.f)-mu*mu;
  const float rstd = rsqrtf(var+EPS_);
  float* orow = out + r*(long)D_;
  orow[tid]     = (v0-mu)*rstd*ldin(s, offS+tid, isbf)     + ldin(b, offB+tid, isbf);
  orow[tid+256] = (v1-mu)*rstd*ldin(s, offS+tid+256, isbf) + ldin(b, offB+tid+256, isbf);
}

// ---------------- causal conv(K=4) + silu ----------------
__global__ void conv_silu(const float* __restrict__ in, int inStride,
                          const void* __restrict__ w, long offW,
                          const void* __restrict__ bias, long offBias,
                          float* __restrict__ out, int Dc,
                          const int* __restrict__ dflag)
{
  const int isbf = *dflag;
  const long total = (long)BT_ * Dc;
  for (long idx = (long)blockIdx.x*256 + threadIdx.x; idx < total;
       idx += (long)gridDim.x*256) {
    const int d = (int)(idx % Dc);
    const long bt = idx / Dc;
    const int b = (int)(bt / T_), t = (int)(bt % T_);
    float a = ldin(bias, offBias + d, isbf);
#pragma unroll
    for (int kk = 0; kk < 4; kk++) {
      const int ts = t - 3 + kk;
      if (ts >= 0) a += ldin(w, offW + kk*Dc + d, isbf) * in[((long)(b*T_+ts))*inStride + d];
    }
    out[idx] = siluf(a);
  }
}

// ---------------- generic tiled GEMM: C(f32) = act(alpha*A(f32)@B(in)+bias) [+C] ----------------
// flags: 1=bias, 2=accumulate into C, 4=gelu
__global__ __launch_bounds__(256) void gemm_f32b(
    const float* __restrict__ A, const void* __restrict__ Bw, long offB,
    const void* __restrict__ bias, long offBias, float* __restrict__ C,
    int M, int N, int K, int lda, int ldb, int ldc,
    long strideA, long strideB, long strideC, long strideBias,
    float alpha, int flags, const int* __restrict__ dflag)
{
  const int isbf = *dflag;
  const int bz = blockIdx.z;
  A  += (long)bz * strideA;
  const long bB = offB + (long)bz * strideB;
  C  += (long)bz * strideC;
  const long bBias = offBias + (long)bz * strideBias;
  __shared__ float sA[16][68];
  __shared__ float sB[16][64];
  const int tid = threadIdx.x;
  const int tx = tid & 15, ty = tid >> 4;
  const int m0 = blockIdx.y * 64, n0 = blockIdx.x * 64;
  float acc[4][4];
#pragma unroll
  for (int i=0;i<4;i++)
#pragma unroll
    for (int j=0;j<4;j++) acc[i][j]=0.f;

  for (int k0 = 0; k0 < K; k0 += 16) {
#pragma unroll
    for (int r = 0; r < 4; r++) {
      int lin = tid + r*256;
      int kk = lin & 15, m = lin >> 4;
      int gm = m0 + m, gk = k0 + kk;
      sA[kk][m] = (gm < M && gk < K) ? A[(long)gm*lda + gk] : 0.f;
    }
#pragma unroll
    for (int r = 0; r < 4; r++) {
      int lin = tid + r*256;
      int nn = lin & 63, kk = lin >> 6;
      int gn = n0 + nn, gk = k0 + kk;
      sB[kk][nn] = (gn < N && gk < K) ? ldin(Bw, bB + (long)gk*ldb + gn, isbf) : 0.f;
    }
    __syncthreads();
#pragma unroll
    for (int kk = 0; kk < 16; kk++) {
      const float4 a4 = *(const float4*)(&sA[kk][ty*4]);
      const float4 b4 = *(const float4*)(&sB[kk][tx*4]);
      float av[4] = {a4.x, a4.y, a4.z, a4.w};
      float bv[4] = {b4.x, b4.y, b4.z, b4.w};
#pragma unroll
      for (int i=0;i<4;i++)
#pragma unroll
        for (int j=0;j<4;j++) acc[i][j] += av[i]*bv[j];
    }
    __syncthreads();
  }
#pragma unroll
  for (int i=0;i<4;i++) {
    const int gm = m0 + ty*4 + i;
    if (gm >= M) continue;
#pragma unroll
    for (int j=0;j<4;j++) {
      const int gn = n0 + tx*4 + j;
      if (gn >= N) continue;
      float vv = acc[i][j]*alpha;
      if (flags & 1) vv += ldin(bias, bBias + gn, isbf);
      if (flags & 4) vv = geluf(vv);
      const long idx = (long)gm*ldc + gn;
      if (flags & 2) vv += C[idx];
      C[idx] = vv;
    }
  }
}

// ---------------- sLSTM recurrent scan: one block per (b, head) ----------------
__global__ __launch_bounds__(256) void slstm_scan(
    const float* __restrict__ g4, const void* __restrict__ Rg, long offR,
    float* __restrict__ hs, const int* __restrict__ dflag)
{
  const int isbf = *dflag;
  const int blk = blockIdx.x;
  const int b = blk >> 3, hd = blk & 7;
  const int tid = threadIdx.x;
  const int g = tid >> 6, e = tid & 63;
  float w[64];
  {
    const long wp = offR + ((long)(g*NH_ + hd)*64)*64 + e;
#pragma unroll
    for (int d = 0; d < 64; d++) w[d] = ldin(Rg, wp + d*64, isbf);
  }
  __shared__ float hlds[64];
  __shared__ float rec[4][64];
  if (tid < 64) hlds[tid] = 0.f;
  float c = 0.f, n = 0.f, m = 0.f;
  __syncthreads();
  const long gate_base = (long)(b*T_)*D_ + hd*64 + e;
  for (int t = 0; t < T_; t++) {
    float r = 0.f;
#pragma unroll
    for (int d4 = 0; d4 < 16; d4++) {
      const float4 hv = *(const float4*)(&hlds[d4*4]);
      r += w[4*d4]*hv.x + w[4*d4+1]*hv.y + w[4*d4+2]*hv.z + w[4*d4+3]*hv.w;
    }
    r += g4[(long)g*BT_*D_ + gate_base + (long)t*D_];
    rec[g][e] = r;
    __syncthreads();
    if (tid < 64) {
      const float it = rec[0][e], ft = rec[1][e];
      const float zt = tanhf(rec[2][e]);
      const float ot = 1.f/(1.f+expf(-rec[3][e]));
      const float mn = fmaxf(ft + m, it);
      const float ig = expf(it - mn);
      const float fg = expf(ft + m - mn);
      c = fg*c + ig*zt;
      n = fg*n + ig;
      m = mn;
      const float hn = ot*c/fmaxf(n, 1e-6f);
      hlds[e] = hn;
      hs[(long)(b*T_+t)*D_ + hd*64 + e] = hn;
    }
    __syncthreads();
  }
}

// ---------------- head_norm(dh=64) * gn, accumulated into h ----------------
__global__ __launch_bounds__(64) void hn_add(
    const float* __restrict__ hs, const void* __restrict__ gn, long offG,
    float* __restrict__ h, const int* __restrict__ dflag)
{
  const int isbf = *dflag;
  const int blk = blockIdx.x;
  const int bt = blk >> 3, hd = blk & 7;
  const int e = threadIdx.x;
  const long idx = (long)bt*D_ + hd*64 + e;
  const float x = hs[idx];
  float s1 = x, s2 = x*x;
#pragma unroll
  for (int o = 32; o > 0; o >>= 1) { s1 += __shfl_xor(s1, o); s2 += __shfl_xor(s2, o); }
  const float mu = s1*(1.f/64.f);
  const float var = s2*(1.f/64.f) - mu*mu;
  const float y = (x-mu)*rsqrtf(var+EPS_)*ldin(gn, offG + hd*64+e, isbf);
  h[idx] += y;
}

// ---------------- FF gating: gelu(g)*up ----------------
__global__ void ffgate(const float* __restrict__ u, float* __restrict__ out)
{
  const long total = (long)BT_*FF_;
  for (long idx = (long)blockIdx.x*256 + threadIdx.x; idx < total;
       idx += (long)gridDim.x*256) {
    const long m = idx / FF_;
    const int j = (int)(idx % FF_);
    const float g = u[m*FF2_ + j];
    out[idx] = geluf(g) * u[m*FF2_ + FF_ + j];
  }
}

// ---------------- mLSTM gate cumsum: one block per (b, head) ----------------
__global__ __launch_bounds__(256) void mlstm_cf(
    const float* __restrict__ g16, float* __restrict__ cf, float* __restrict__ logi)
{
  const int bh = blockIdx.x;
  const int b = bh >> 3, hd = bh & 7;
  const int tid = threadIdx.x;
  __shared__ float slf[T_];
  if (tid < T_) {
    const float gf = g16[(long)(b*T_+tid)*16 + 8 + hd];
    const float ls = (gf >= 0.f) ? -log1pf(expf(-gf)) : (gf - log1pf(expf(gf)));
    slf[tid] = ls;
    logi[(long)bh*T_ + tid] = g16[(long)(b*T_+tid)*16 + hd];
  }
  __syncthreads();
  if (tid == 0) {
    float a = 0.f;
    for (int t = 0; t < T_; t++) { a += slf[t]; slf[t] = a; }
  }
  __syncthreads();
  if (tid < T_) cf[(long)bh*T_ + tid] = slf[tid];
}

// ---------------- mLSTM attention row: one block per (b, head, t) ----------------
__global__ __launch_bounds__(256) void mlstm_attn(
    const float* __restrict__ q, const float* __restrict__ k,
    const float* __restrict__ v, const float* __restrict__ cf,
    const float* __restrict__ logi, float* __restrict__ hatt)
{
  const int blk = blockIdx.x;
  const int t = blk % T_;
  const int bh = blk / T_;
  const int hd = bh & 7, b = bh >> 3;
  const int tid = threadIdx.x;
  __shared__ float sq[128];
  __shared__ float sS[256];
  __shared__ float red[256];
  const long rowq = ((long)(b*T_+t))*DI_ + hd*DHI_;
  if (tid < 128) sq[tid] = q[rowq + tid];
  __syncthreads();
  const int s = tid;
  float dm = -INFINITY, qk = 0.f;
  if (s <= t) {
    const float* kr = k + ((long)(b*T_+s))*DI_ + hd*DHI_;
    float a = 0.f;
#pragma unroll
    for (int d = 0; d < 128; d += 4) {
      const float4 kv = *(const float4*)(kr + d);
      const float4 qv = *(const float4*)(&sq[d]);
      a += qv.x*kv.x + qv.y*kv.y + qv.z*kv.z + qv.w*kv.w;
    }
    qk = a;
    dm = cf[(long)bh*T_ + t] - cf[(long)bh*T_ + s] + logi[(long)bh*T_ + s];
  }
  red[tid] = dm; __syncthreads();
  for (int o = 128; o > 0; o >>= 1) {
    if (tid < o) red[tid] = fmaxf(red[tid], red[tid+o]);
    __syncthreads();
  }
  const float m = red[0];
  __syncthreads();
  const float Sv = (s <= t) ? qk * expf(dm - m) : 0.f;
  sS[tid] = Sv;
  red[tid] = Sv; __syncthreads();
  for (int o = 128; o > 0; o >>= 1) {
    if (tid < o) red[tid] += red[tid+o];
    __syncthreads();
  }
  const float ssum = red[0];
  const float inv = 1.f / fmaxf(fabsf(ssum), expf(-m));
  if (tid < 128) {
    float a = 0.f;
    const float* vb = v + ((long)(b*T_))*DI_ + hd*DHI_ + tid;
#pragma unroll 4
    for (int s2 = 0; s2 <= t; s2++) a += sS[s2] * vb[(long)s2*DI_];
    hatt[rowq + tid] = a * inv;
  }
}

// ---------------- head_norm(dh=128)*gn + skip*xc, then *silu(z) ----------------
__global__ __launch_bounds__(128) void hn_mlstm(
    const float* __restrict__ hatt, const void* __restrict__ gn, long offG,
    const void* __restrict__ skip, long offSk, const float* __restrict__ xc,
    const float* __restrict__ u, float* __restrict__ gin,
    const int* __restrict__ dflag)
{
  const int isbf = *dflag;
  const int blk = blockIdx.x;
  const int bt = blk >> 3, hd = blk & 7;
  const int e = threadIdx.x;
  const int j = hd*DHI_ + e;
  const long idx = (long)bt*DI_ + j;
  const float x = hatt[idx];
  __shared__ float r1[128], r2[128];
  r1[e]=x; r2[e]=x*x; __syncthreads();
  for (int o=64;o>0;o>>=1){ if(e<o){r1[e]+=r1[e+o]; r2[e]+=r2[e+o];} __syncthreads(); }
  const float mu = r1[0]*(1.f/128.f);
  const float var = r2[0]*(1.f/128.f)-mu*mu;
  const float y = (x-mu)*rsqrtf(var+EPS_)*ldin(gn, offG+j, isbf) + ldin(skip, offSk+j, isbf)*xc[idx];
  const float z = u[(long)bt*2048 + DI_ + j];
  gin[idx] = y * siluf(z);
}

// ---------------- final transpose to output ----------------
__global__ void out_transpose(const float* __restrict__ hp, void* __restrict__ out,
                              const int* __restrict__ dflag)
{
  const int isbf = *dflag;
  const int tid = threadIdx.x;
  if (tid < B_*6) {
    const int b = tid / 6, hd = tid % 6;
    const float v = hp[hd*B_ + b];
    if (isbf) ((bf16*)out)[tid] = __float2bfloat16(v);
    else      ((float*)out)[tid] = v;
  }
}

extern "C" void kernel_launch(void* const* d_in, const int* in_sizes, int n_in,
                              void* d_out, int out_size, void* d_ws, size_t ws_size,
                              hipStream_t stream)
{
  (void)in_sizes; (void)n_in; (void)out_size; (void)ws_size;
  const void* x        = d_in[0];
  const void* w_in     = d_in[1];
  const void* b_in     = d_in[2];
  const void* ln_in_s  = d_in[3];
  const void* ln_in_b  = d_in[4];
  const void* s_ln_s   = d_in[5];
  const void* s_ln_b   = d_in[6];
  const void* s_conv_w = d_in[7];
  const void* s_conv_b = d_in[8];
  const void* s_wg     = d_in[9];
  const void* s_rg     = d_in[10];
  const void* s_bg     = d_in[11];
  const void* s_gn     = d_in[12];
  const void* s_ffln_s = d_in[13];
  const void* s_ffln_b = d_in[14];
  const void* s_ff_w1  = d_in[15];
  const void* s_ff_w2  = d_in[16];
  const void* m_ln_s   = d_in[17];
  const void* m_ln_b   = d_in[18];
  const void* m_w_up   = d_in[19];
  const void* m_conv_w = d_in[20];
  const void* m_conv_b = d_in[21];
  const void* m_wq     = d_in[22];
  const void* m_wk     = d_in[23];
  const void* m_wv     = d_in[24];
  const void* m_w_if   = d_in[25];
  const void* m_b_if   = d_in[26];
  const void* m_skip   = d_in[27];
  const void* m_gn     = d_in[28];
  const void* m_w_down = d_in[29];
  const void* post_ln_s= d_in[30];
  const void* post_ln_b= d_in[31];
  const void* hw1      = d_in[32];
  const void* hb1      = d_in[33];
  const void* hw2      = d_in[34];
  const void* hb2      = d_in[35];
  const void* hw3      = d_in[36];
  const void* hb3      = d_in[37];

  float* W   = (float*)d_ws;
  float* h   = W;                  // BT*D
  float* xn  = W + 4128768L;       // BT*D
  float* xc  = W + 8257536L;       // BT*DI
  float* u   = W + 16515072L;      // 4*BT*D (sLSTM gates / mLSTM up-proj / FF u)
  float* q   = W + 33030144L;      // BT*DI (also hs, ffg, hatt in-place, gin)
  float* k   = W + 41287680L;      // BT*DI
  float* v   = W + 49545216L;      // BT*DI
  float* g16 = W + 57802752L;      // BT*16
  float* cfb = W + 57931776L;      // B*NH*T
  float* lib = W + 57996288L;      // B*NH*T
  float* last= W + 58060800L;      // 32*512
  float* ha1 = W + 58077184L;      // 6*32*256
  float* ha2 = W + 58126336L;      // 6*32*128
  float* hp  = W + 58150912L;      // 6*32
  int*   dfl = (int*)(W + 58151168L);

  const float kscale = 0.08838834764831845f; // 1/sqrt(128)

  detect_dtype<<<1, 64, 0, stream>>>((const unsigned*)ln_in_s, dfl);

  ln_proj<<<BT_, 256, 0, stream>>>(x, w_in, b_in, ln_in_s, ln_in_b, h, dfl);

  int si = 0, mi = 0;
  for (int blk = 0; blk < 7; blk++) {
    if ((blk & 1) == 0) {
      // ---- sLSTM block ----
      ln_rows<<<BT_,256,0,stream>>>(h, 512L, s_ln_s, (long)si*512, s_ln_b, (long)si*512, xn, dfl);
      {
        long tot = (long)BT_*512; int g = (int)((tot+255)/256);
        conv_silu<<<g,256,0,stream>>>(xn, 512, s_conv_w, (long)si*4*512, s_conv_b, (long)si*512, xc, 512, dfl);
      }
      for (int g = 0; g < 4; g++) {
        const float* Ain = (g < 2) ? xc : xn;  // i,f from conv; z,o from normed x
        gemm_f32b<<<dim3(8,126,1),256,0,stream>>>(Ain, s_wg, ((long)(si*4+g))*512*512,
            s_bg, (long)(si*4+g)*512, u + (long)g*BT_*512,
            BT_, 512, 512, 512, 512, 512, 0,0,0,0, 1.f, 1, dfl);
      }
      slstm_scan<<<256,256,0,stream>>>(u, s_rg, (long)si*4*8*64*64, q /*hs*/, dfl);
      hn_add<<<BT_*8,64,0,stream>>>(q, s_gn, (long)si*512, h, dfl);
      // ---- FF block ----
      ln_rows<<<BT_,256,0,stream>>>(h, 512L, s_ffln_s, (long)si*512, s_ffln_b, (long)si*512, xn, dfl);
      gemm_f32b<<<dim3(22,126,1),256,0,stream>>>(xn, s_ff_w1, (long)si*512*1364, nullptr, 0,
            u, BT_, 1364, 512, 512, 1364, 1364, 0,0,0,0, 1.f, 0, dfl);
      {
        long tot = (long)BT_*FF_; int g = (int)((tot+255)/256);
        ffgate<<<g,256,0,stream>>>(u, q /*ffg*/);
      }
      gemm_f32b<<<dim3(8,126,1),256,0,stream>>>(q, s_ff_w2, (long)si*682*512, nullptr, 0,
            h, BT_, 512, 682, 682, 512, 512, 0,0,0,0, 1.f, 2, dfl);
      si++;
    } else {
      // ---- mLSTM block ----
      ln_rows<<<BT_,256,0,stream>>>(h, 512L, m_ln_s, (long)mi*512, m_ln_b, (long)mi*512, xn, dfl);
      gemm_f32b<<<dim3(32,126,1),256,0,stream>>>(xn, m_w_up, (long)mi*512*2048, nullptr, 0,
            u, BT_, 2048, 512, 512, 2048, 2048, 0,0,0,0, 1.f, 0, dfl);
      {
        long tot = (long)BT_*1024; int g = (int)((tot+255)/256);
        conv_silu<<<g,256,0,stream>>>(u, 2048, m_conv_w, (long)mi*4*1024, m_conv_b, (long)mi*1024, xc, 1024, dfl);
      }
      // per-head q,k,v (grid.z = head)
      gemm_f32b<<<dim3(2,126,8),256,0,stream>>>(xc, m_wq, (long)mi*8*128*128, nullptr, 0,
            q, BT_, 128, 128, 1024, 128, 1024, 128, 16384, 128, 0, 1.f, 0, dfl);
      gemm_f32b<<<dim3(2,126,8),256,0,stream>>>(xc, m_wk, (long)mi*8*128*128, nullptr, 0,
            k, BT_, 128, 128, 1024, 128, 1024, 128, 16384, 128, 0, kscale, 0, dfl);
      gemm_f32b<<<dim3(2,126,8),256,0,stream>>>(u, m_wv, (long)mi*8*128*128, nullptr, 0,
            v, BT_, 128, 128, 2048, 128, 1024, 128, 16384, 128, 0, 1.f, 0, dfl);
      gemm_f32b<<<dim3(1,126,1),256,0,stream>>>(xc, m_w_if, (long)mi*1024*16, m_b_if, (long)mi*16,
            g16, BT_, 16, 1024, 1024, 16, 16, 0,0,0,0, 1.f, 1, dfl);
      mlstm_cf<<<256,256,0,stream>>>(g16, cfb, lib);
      mlstm_attn<<<B_*8*T_,256,0,stream>>>(q, k, v, cfb, lib, q /*hatt in-place*/);
      hn_mlstm<<<BT_*8,128,0,stream>>>(q, m_gn, (long)mi*1024, m_skip, (long)mi*1024, xc, u, q, dfl);
      gemm_f32b<<<dim3(8,126,1),256,0,stream>>>(q, m_w_down, (long)mi*1024*512, nullptr, 0,
            h, BT_, 512, 1024, 1024, 512, 512, 0,0,0,0, 1.f, 2, dfl);
      mi++;
    }
  }

  // post-LN on last timestep rows only
  ln_rows<<<B_,256,0,stream>>>(h + (long)(T_-1)*512, (long)T_*512, post_ln_s, 0, post_ln_b, 0, last, dfl);

  // 6 prediction heads, batched over grid.z
  gemm_f32b<<<dim3(4,1,6),256,0,stream>>>(last, hw1, 0, hb1, 0, ha1, 32, 256, 512, 512, 256, 256,
        0, 512L*256, 32L*256, 256, 1.f, 1|4, dfl);
  gemm_f32b<<<dim3(2,1,6),256,0,stream>>>(ha1, hw2, 0, hb2, 0, ha2, 32, 128, 256, 256, 128, 128,
        32L*256, 256L*128, 32L*128, 128, 1.f, 1|4, dfl);
  gemm_f32b<<<dim3(1,1,6),256,0,stream>>>(ha2, hw3, 0, hb3, 0, hp, 32, 1, 128, 128, 1, 1,
        32L*128, 128L, 32L, 1, 1.f, 1, dfl);
  out_transpose<<<1,256,0,stream>>>(hp, d_out, dfl);
}

// Round 3
// 7454.697 us; speedup vs baseline: 1.2649x; 1.2649x over previous
//
#include <hip/hip_runtime.h>
#include <hip/hip_bf16.h>
#include <cmath>

typedef __hip_bfloat16 bf16;

#define B_   32
#define T_   252
#define F_   8
#define D_   512
#define NH_  8
#define DH_  64
#define DI_  1024
#define DHI_ 128
#define FF_  682
#define FF2_ 1364
#define BT_  (B_*T_)
#define EPS_ 1e-5f

typedef __attribute__((ext_vector_type(8))) short short8;
typedef __attribute__((ext_vector_type(4))) float floatx4;

__device__ __forceinline__ float b2f(bf16 v){ return __bfloat162float(v); }
__device__ __forceinline__ float siluf(float x){ return x/(1.f+expf(-x)); }
__device__ __forceinline__ float geluf(float x){
  float x3 = x*x*x;
  return 0.5f*x*(1.f+tanhf(0.7978845608028654f*(x+0.044715f*x3)));
}
// dtype-robust input load: harness may store float inputs as bf16 or fp32
__device__ __forceinline__ float ldin(const void* p, long i, int isbf){
  return isbf ? __bfloat162float(((const bf16*)p)[i]) : ((const float*)p)[i];
}
__device__ __forceinline__ unsigned short f2bu(float f){
  bf16 h = __float2bfloat16(f);
  return *(reinterpret_cast<unsigned short*>(&h));
}
__device__ __forceinline__ unsigned packbf(float x, float y){
  return (unsigned)f2bu(x) | ((unsigned)f2bu(y) << 16);
}
__device__ __forceinline__ float bflo(unsigned u_){
  return __uint_as_float((u_ & 0xFFFFu) << 16);
}
__device__ __forceinline__ float bfhi(unsigned u_){
  return __uint_as_float(u_ & 0xFFFF0000u);
}

__global__ void detect_dtype(const unsigned* __restrict__ probe, int* __restrict__ flag)
{
  if (threadIdx.x == 0) *flag = (*probe == 0x3F803F80u) ? 1 : 0;
}

// ---------------- weight transpose + bf16 cast: in [K][N] -> out bf16 [N][K] ----------------
__global__ __launch_bounds__(256) void wt_transpose(
    const void* __restrict__ in, long inOff, long inStride, int K, int N,
    unsigned short* __restrict__ out, long outStride, const int* __restrict__ dflag)
{
  const int isbf = *dflag;
  const int bz = blockIdx.z;
  const long base = inOff + (long)bz*inStride;
  unsigned short* op = out + (long)bz*outStride;
  __shared__ float tile[32][33];
  const int k0 = blockIdx.y*32, n0 = blockIdx.x*32;
  const int tn = threadIdx.x & 31, tk = threadIdx.x >> 5;
#pragma unroll
  for (int i=0;i<4;i++){
    int kk = tk + i*8;
    float v = 0.f;
    if (k0+kk < K && n0+tn < N) v = ldin(in, base + (long)(k0+kk)*N + n0+tn, isbf);
    tile[kk][tn] = v;
  }
  __syncthreads();
#pragma unroll
  for (int i=0;i<4;i++){
    int nn = tk + i*8;
    if (n0+nn < N && k0+tn < K)
      op[(long)(n0+nn)*K + k0+tn] = f2bu(tile[tn][nn]);
  }
}

// ---------------- bf16 MFMA GEMM: C(f32) = alpha*A(f32)@B + [bias] [+C] ----------------
// A: fp32 [M=8064][lda] (grid.y=63 tiles of 128) ; BT: bf16 [N][K] row-major (k-contig)
// flags: 1=bias, 2=accumulate
__global__ __launch_bounds__(256) void gemm_mfma(
    const float* __restrict__ A, const unsigned short* __restrict__ BT,
    const void* __restrict__ bias, long offBias, float* __restrict__ C,
    int N, int K, int lda, int ldc,
    long strideA, long strideBT, long strideC, long strideBias,
    float alpha, int flags, const int* __restrict__ dflag)
{
  const int isbf = *dflag;
  const int bz = blockIdx.z;
  A  += (long)bz * strideA;
  BT += (long)bz * strideBT;
  C  += (long)bz * strideC;
  const long bBias = offBias + (long)bz * strideBias;

  __shared__ unsigned short sA[128*40];
  __shared__ unsigned short sB[128*40];
  const int tid = threadIdx.x;
  const int wid = tid >> 6, lane = tid & 63;
  const int wm = (wid >> 1)*64, wn = (wid & 1)*64;
  const int m0 = blockIdx.y*128, n0 = blockIdx.x*128;
  const int lr = lane & 15, lq = lane >> 4;

  floatx4 acc[4][4];
#pragma unroll
  for (int mi=0;mi<4;mi++)
#pragma unroll
    for (int ni=0;ni<4;ni++)
#pragma unroll
      for (int r=0;r<4;r++) acc[mi][ni][r] = 0.f;

  const int rS = tid >> 1, kh = (tid & 1)*16;

  for (int k0 = 0; k0 < K; k0 += 32) {
    // stage A tile (fp32 -> bf16), rows m0..m0+127, k0..k0+31
    {
      const float* ap = A + (long)(m0 + rS)*lda + k0 + kh;
#pragma unroll
      for (int c8=0;c8<4;c8++){
        int kb = k0 + kh + c8*4;
        unsigned short t0_=0,t1_=0,t2_=0,t3_=0;
        if (kb   < K) t0_ = f2bu(ap[c8*4+0]);
        if (kb+1 < K) t1_ = f2bu(ap[c8*4+1]);
        if (kb+2 < K) t2_ = f2bu(ap[c8*4+2]);
        if (kb+3 < K) t3_ = f2bu(ap[c8*4+3]);
        uint2 pk;
        pk.x = (unsigned)t0_ | ((unsigned)t1_<<16);
        pk.y = (unsigned)t2_ | ((unsigned)t3_<<16);
        *(uint2*)&sA[rS*40 + kh + c8*4] = pk;
      }
    }
    // stage B tile: BT rows n0..n0+127, k0..k0+31 (already bf16, k-contig)
    {
      const int gn = n0 + rS;
#pragma unroll
      for (int c8=0;c8<4;c8++){
        int kb = k0 + kh + c8*4;
        unsigned short b0=0,b1=0,b2=0,b3=0;
        if (gn < N) {
          const unsigned short* bp = BT + (long)gn*K + kb;
          if (kb   < K) b0 = bp[0];
          if (kb+1 < K) b1 = bp[1];
          if (kb+2 < K) b2 = bp[2];
          if (kb+3 < K) b3 = bp[3];
        }
        uint2 pk;
        pk.x = (unsigned)b0 | ((unsigned)b1<<16);
        pk.y = (unsigned)b2 | ((unsigned)b3<<16);
        *(uint2*)&sB[rS*40 + kh + c8*4] = pk;
      }
    }
    __syncthreads();

    short8 af[4], bf_[4];
#pragma unroll
    for (int mi=0;mi<4;mi++)
      af[mi] = *(const short8*)&sA[(wm + mi*16 + lr)*40 + lq*8];
#pragma unroll
    for (int ni=0;ni<4;ni++)
      bf_[ni] = *(const short8*)&sB[(wn + ni*16 + lr)*40 + lq*8];
#pragma unroll
    for (int mi=0;mi<4;mi++)
#pragma unroll
      for (int ni=0;ni<4;ni++)
        acc[mi][ni] = __builtin_amdgcn_mfma_f32_16x16x32_bf16(af[mi], bf_[ni], acc[mi][ni], 0,0,0);
    __syncthreads();
  }

  // epilogue: D row = lq*4 + rr, col = lr  (m89-verified layout)
#pragma unroll
  for (int mi=0;mi<4;mi++){
#pragma unroll
    for (int ni=0;ni<4;ni++){
      const int gn = n0 + wn + ni*16 + lr;
      if (gn >= N) continue;
      float bv = (flags & 1) ? ldin(bias, bBias + gn, isbf) : 0.f;
#pragma unroll
      for (int rr=0;rr<4;rr++){
        const int gm = m0 + wm + mi*16 + lq*4 + rr;
        float vv = acc[mi][ni][rr]*alpha + bv;
        const long idx = (long)gm*ldc + gn;
        if (flags & 2) vv += C[idx];
        C[idx] = vv;
      }
    }
  }
}

// ---------------- input projection + layernorm ----------------
__global__ __launch_bounds__(256) void ln_proj(
    const void* __restrict__ x, const void* __restrict__ w,
    const void* __restrict__ bb, const void* __restrict__ s,
    const void* __restrict__ b, float* __restrict__ out,
    const int* __restrict__ dflag)
{
  const int isbf = *dflag;
  const int r = blockIdx.x;
  const int tid = threadIdx.x;
  float xr[8];
#pragma unroll
  for (int f = 0; f < 8; f++) xr[f] = ldin(x, (long)r*8+f, isbf);
  float vv[2];
#pragma unroll
  for (int i2 = 0; i2 < 2; i2++) {
    const int j = tid + i2*256;
    float a = ldin(bb, j, isbf);
#pragma unroll
    for (int f = 0; f < 8; f++) a += xr[f]*ldin(w, f*512+j, isbf);
    vv[i2] = a;
  }
  __shared__ float r1[256], r2[256];
  r1[tid] = vv[0]+vv[1]; r2[tid] = vv[0]*vv[0]+vv[1]*vv[1];
  __syncthreads();
  for (int o = 128; o > 0; o >>= 1) {
    if (tid < o) { r1[tid]+=r1[tid+o]; r2[tid]+=r2[tid+o]; }
    __syncthreads();
  }
  const float mu = r1[0]*(1.f/512.f);
  const float var = r2[0]*(1.f/512.f)-mu*mu;
  const float rstd = rsqrtf(var+EPS_);
  float* orow = out + (long)r*512;
#pragma unroll
  for (int i2 = 0; i2 < 2; i2++) {
    const int j = tid + i2*256;
    orow[j] = (vv[i2]-mu)*rstd*ldin(s, j, isbf) + ldin(b, j, isbf);
  }
}

// ---------------- layernorm over 512-elem rows ----------------
__global__ __launch_bounds__(256) void ln_rows(
    const float* __restrict__ in, long rowStride,
    const void* __restrict__ s, long offS,
    const void* __restrict__ b, long offB,
    float* __restrict__ out, const int* __restrict__ dflag)
{
  const int isbf = *dflag;
  const long r = blockIdx.x;
  const int tid = threadIdx.x;
  const float* xr = in + r*rowStride;
  const float v0 = xr[tid], v1 = xr[tid+256];
  __shared__ float r1[256], r2[256];
  r1[tid] = v0+v1; r2[tid] = v0*v0+v1*v1;
  __syncthreads();
  for (int o = 128; o > 0; o >>= 1) {
    if (tid < o) { r1[tid]+=r1[tid+o]; r2[tid]+=r2[tid+o]; }
    __syncthreads();
  }
  const float mu = r1[0]*(1.f/512.f);
  const float var = r2[0]*(1.f/512.f)-mu*mu;
  const float rstd = rsqrtf(var+EPS_);
  float* orow = out + r*(long)D_;
  orow[tid]     = (v0-mu)*rstd*ldin(s, offS+tid, isbf)     + ldin(b, offB+tid, isbf);
  orow[tid+256] = (v1-mu)*rstd*ldin(s, offS+tid+256, isbf) + ldin(b, offB+tid+256, isbf);
}

// ---------------- causal conv(K=4) + silu ----------------
__global__ void conv_silu(const float* __restrict__ in, int inStride,
                          const void* __restrict__ w, long offW,
                          const void* __restrict__ bias, long offBias,
                          float* __restrict__ out, int Dc,
                          const int* __restrict__ dflag)
{
  const int isbf = *dflag;
  const long total = (long)BT_ * Dc;
  for (long idx = (long)blockIdx.x*256 + threadIdx.x; idx < total;
       idx += (long)gridDim.x*256) {
    const int d = (int)(idx % Dc);
    const long bt = idx / Dc;
    const int b = (int)(bt / T_), t = (int)(bt % T_);
    float a = ldin(bias, offBias + d, isbf);
#pragma unroll
    for (int kk = 0; kk < 4; kk++) {
      const int ts = t - 3 + kk;
      if (ts >= 0) a += ldin(w, offW + kk*Dc + d, isbf) * in[((long)(b*T_+ts))*inStride + d];
    }
    out[idx] = siluf(a);
  }
}

// ---------------- fallback SIMT GEMM (small shapes + low-ws fallback) ----------------
// flags: 1=bias, 2=accumulate into C, 4=gelu
__global__ __launch_bounds__(256) void gemm_f32b(
    const float* __restrict__ A, const void* __restrict__ Bw, long offB,
    const void* __restrict__ bias, long offBias, float* __restrict__ C,
    int M, int N, int K, int lda, int ldb, int ldc,
    long strideA, long strideB, long strideC, long strideBias,
    float alpha, int flags, const int* __restrict__ dflag)
{
  const int isbf = *dflag;
  const int bz = blockIdx.z;
  A  += (long)bz * strideA;
  const long bB = offB + (long)bz * strideB;
  C  += (long)bz * strideC;
  const long bBias = offBias + (long)bz * strideBias;
  __shared__ float sA[16][68];
  __shared__ float sB[16][64];
  const int tid = threadIdx.x;
  const int tx = tid & 15, ty = tid >> 4;
  const int m0 = blockIdx.y * 64, n0 = blockIdx.x * 64;
  float acc[4][4];
#pragma unroll
  for (int i=0;i<4;i++)
#pragma unroll
    for (int j=0;j<4;j++) acc[i][j]=0.f;

  for (int k0 = 0; k0 < K; k0 += 16) {
#pragma unroll
    for (int r = 0; r < 4; r++) {
      int lin = tid + r*256;
      int kk = lin & 15, m = lin >> 4;
      int gm = m0 + m, gk = k0 + kk;
      sA[kk][m] = (gm < M && gk < K) ? A[(long)gm*lda + gk] : 0.f;
    }
#pragma unroll
    for (int r = 0; r < 4; r++) {
      int lin = tid + r*256;
      int nn = lin & 63, kk = lin >> 6;
      int gn = n0 + nn, gk = k0 + kk;
      sB[kk][nn] = (gn < N && gk < K) ? ldin(Bw, bB + (long)gk*ldb + gn, isbf) : 0.f;
    }
    __syncthreads();
#pragma unroll
    for (int kk = 0; kk < 16; kk++) {
      const float4 a4 = *(const float4*)(&sA[kk][ty*4]);
      const float4 b4 = *(const float4*)(&sB[kk][tx*4]);
      float av[4] = {a4.x, a4.y, a4.z, a4.w};
      float bv[4] = {b4.x, b4.y, b4.z, b4.w};
#pragma unroll
      for (int i=0;i<4;i++)
#pragma unroll
        for (int j=0;j<4;j++) acc[i][j] += av[i]*bv[j];
    }
    __syncthreads();
  }
#pragma unroll
  for (int i=0;i<4;i++) {
    const int gm = m0 + ty*4 + i;
    if (gm >= M) continue;
#pragma unroll
    for (int j=0;j<4;j++) {
      const int gn = n0 + tx*4 + j;
      if (gn >= N) continue;
      float vv = acc[i][j]*alpha;
      if (flags & 1) vv += ldin(bias, bBias + gn, isbf);
      if (flags & 4) vv = geluf(vv);
      const long idx = (long)gm*ldc + gn;
      if (flags & 2) vv += C[idx];
      C[idx] = vv;
    }
  }
}

// ---------------- sLSTM recurrent scan: one block per (b, head) ----------------
__global__ __launch_bounds__(256) void slstm_scan(
    const float* __restrict__ g4, const void* __restrict__ Rg, long offR,
    float* __restrict__ hs, const int* __restrict__ dflag)
{
  const int isbf = *dflag;
  const int blk = blockIdx.x;
  const int b = blk >> 3, hd = blk & 7;
  const int tid = threadIdx.x;
  const int g = tid >> 6, e = tid & 63;
  float w[64];
  {
    const long wp = offR + ((long)(g*NH_ + hd)*64)*64 + e;
#pragma unroll
    for (int d = 0; d < 64; d++) w[d] = ldin(Rg, wp + d*64, isbf);
  }
  __shared__ float hlds[64];
  __shared__ float rec[4][64];
  if (tid < 64) hlds[tid] = 0.f;
  float c = 0.f, n = 0.f, m = 0.f;
  __syncthreads();
  const long gate_base = (long)(b*T_)*D_ + hd*64 + e;
  for (int t = 0; t < T_; t++) {
    float r = 0.f;
#pragma unroll
    for (int d4 = 0; d4 < 16; d4++) {
      const float4 hv = *(const float4*)(&hlds[d4*4]);
      r += w[4*d4]*hv.x + w[4*d4+1]*hv.y + w[4*d4+2]*hv.z + w[4*d4+3]*hv.w;
    }
    r += g4[(long)g*BT_*D_ + gate_base + (long)t*D_];
    rec[g][e] = r;
    __syncthreads();
    if (tid < 64) {
      const float it = rec[0][e], ft = rec[1][e];
      const float zt = tanhf(rec[2][e]);
      const float ot = 1.f/(1.f+expf(-rec[3][e]));
      const float mn = fmaxf(ft + m, it);
      const float ig = expf(it - mn);
      const float fg = expf(ft + m - mn);
      c = fg*c + ig*zt;
      n = fg*n + ig;
      m = mn;
      const float hn = ot*c/fmaxf(n, 1e-6f);
      hlds[e] = hn;
      hs[(long)(b*T_+t)*D_ + hd*64 + e] = hn;
    }
    __syncthreads();
  }
}

// ---------------- head_norm(dh=64) * gn, accumulated into h ----------------
__global__ __launch_bounds__(64) void hn_add(
    const float* __restrict__ hs, const void* __restrict__ gn, long offG,
    float* __restrict__ h, const int* __restrict__ dflag)
{
  const int isbf = *dflag;
  const int blk = blockIdx.x;
  const int bt = blk >> 3, hd = blk & 7;
  const int e = threadIdx.x;
  const long idx = (long)bt*D_ + hd*64 + e;
  const float x = hs[idx];
  float s1 = x, s2 = x*x;
#pragma unroll
  for (int o = 32; o > 0; o >>= 1) { s1 += __shfl_xor(s1, o); s2 += __shfl_xor(s2, o); }
  const float mu = s1*(1.f/64.f);
  const float var = s2*(1.f/64.f) - mu*mu;
  const float y = (x-mu)*rsqrtf(var+EPS_)*ldin(gn, offG + hd*64+e, isbf);
  h[idx] += y;
}

// ---------------- FF gating: gelu(g)*up ----------------
__global__ void ffgate(const float* __restrict__ u, float* __restrict__ out)
{
  const long total = (long)BT_*FF_;
  for (long idx = (long)blockIdx.x*256 + threadIdx.x; idx < total;
       idx += (long)gridDim.x*256) {
    const long m = idx / FF_;
    const int j = (int)(idx % FF_);
    const float g = u[m*FF2_ + j];
    out[idx] = geluf(g) * u[m*FF2_ + FF_ + j];
  }
}

// ---------------- mLSTM gate cumsum: one block per (b, head) ----------------
__global__ __launch_bounds__(256) void mlstm_cf(
    const float* __restrict__ g16, float* __restrict__ cf, float* __restrict__ logi)
{
  const int bh = blockIdx.x;
  const int b = bh >> 3, hd = bh & 7;
  const int tid = threadIdx.x;
  __shared__ float slf[T_];
  if (tid < T_) {
    const float gf = g16[(long)(b*T_+tid)*16 + 8 + hd];
    const float ls = (gf >= 0.f) ? -log1pf(expf(-gf)) : (gf - log1pf(expf(gf)));
    slf[tid] = ls;
    logi[(long)bh*T_ + tid] = g16[(long)(b*T_+tid)*16 + hd];
  }
  __syncthreads();
  if (tid == 0) {
    float a = 0.f;
    for (int t = 0; t < T_; t++) { a += slf[t]; slf[t] = a; }
  }
  __syncthreads();
  if (tid < T_) cf[(long)bh*T_ + tid] = slf[tid];
}

// ---------------- flash-tiled mLSTM attention ----------------
// grid: (4 t-tiles of 64, 256 bh); 256 threads as (ti=tid>>4, si=tid&15)
#define APD 67
__global__ __launch_bounds__(256) void attn_flash(
    const float* __restrict__ q, const float* __restrict__ k,
    const float* __restrict__ v, const float* __restrict__ cf,
    const float* __restrict__ li, float* __restrict__ hatt)
{
  const int tt = blockIdx.x, bh = blockIdx.y;
  const int b = bh >> 3, hd = bh & 7;
  const int t0 = tt*64;
  const int tid = threadIdx.x;
  const int ti = tid >> 4, si = tid & 15;

  __shared__ unsigned sQ[64*APD];
  __shared__ unsigned sK[64*APD];
  __shared__ unsigned sV[64*APD];
  __shared__ unsigned sS[64*33];
  __shared__ float sM[64], sSum[64], scft[64], scfs[64], slis[64];

  for (int idx = tid; idx < 64*64; idx += 256) {
    int r = idx >> 6, kp = idx & 63;
    int t = t0 + r;
    unsigned pk = 0;
    if (t < T_) {
      const float* qp = q + ((long)(b*T_+t))*DI_ + hd*DHI_ + kp*2;
      pk = packbf(qp[0], qp[1]);
    }
    sQ[r*APD + kp] = pk;
  }
  if (tid < 64) {
    int t = t0 + tid;
    scft[tid] = (t < T_) ? cf[(long)bh*T_ + t] : 0.f;
    sM[tid] = -INFINITY; sSum[tid] = 0.f;
  }

  float o[4][4][2];
#pragma unroll
  for (int i=0;i<4;i++)
#pragma unroll
    for (int j=0;j<4;j++){ o[i][j][0]=0.f; o[i][j][1]=0.f; }
  float alpha_[4];

  for (int st = 0; st <= tt; st++) {
    const int s0 = st*64;
    for (int idx = tid; idx < 64*64; idx += 256) {
      int r = idx >> 6, kp = idx & 63;
      int s = s0 + r;
      unsigned pkk = 0, pkv = 0;
      if (s < T_) {
        const float* kpp = k + ((long)(b*T_+s))*DI_ + hd*DHI_ + kp*2;
        const float* vpp = v + ((long)(b*T_+s))*DI_ + hd*DHI_ + kp*2;
        pkk = packbf(kpp[0], kpp[1]);
        pkv = packbf(vpp[0], vpp[1]);
      }
      sK[r*APD + kp] = pkk;
      sV[r*APD + kp] = pkv;
    }
    if (tid < 64) {
      int s = s0 + tid;
      scfs[tid] = (s < T_) ? cf[(long)bh*T_ + s] : 0.f;
      slis[tid] = (s < T_) ? li[(long)bh*T_ + s] : 0.f;
    }
    __syncthreads();

    // ---- S = QK^T on this 64x64 tile ----
    float qk[4][4];
#pragma unroll
    for (int i=0;i<4;i++)
#pragma unroll
      for (int j=0;j<4;j++) qk[i][j]=0.f;
    for (int kp = 0; kp < 64; kp++) {
      float qa0[4], qa1[4], kb0[4], kb1[4];
#pragma unroll
      for (int i=0;i<4;i++){
        unsigned uu = sQ[(ti*4+i)*APD + kp];
        qa0[i] = bflo(uu); qa1[i] = bfhi(uu);
      }
#pragma unroll
      for (int j=0;j<4;j++){
        unsigned uu = sK[(si*4+j)*APD + kp];
        kb0[j] = bflo(uu); kb1[j] = bfhi(uu);
      }
#pragma unroll
      for (int i=0;i<4;i++)
#pragma unroll
        for (int j=0;j<4;j++)
          qk[i][j] += qa0[i]*kb0[j] + qa1[i]*kb1[j];
    }

    // ---- decay matrix, online max/sum, S scaling ----
#pragma unroll
    for (int i=0;i<4;i++){
      const int tg = t0 + ti*4 + i;
      float dmv[4];
      float mx = -INFINITY;
#pragma unroll
      for (int j=0;j<4;j++){
        const int sg = s0 + si*4 + j;
        const bool valid = (tg < T_) && (sg <= tg);
        dmv[j] = valid ? (scft[ti*4+i] - scfs[si*4+j] + slis[si*4+j]) : -INFINITY;
        mx = fmaxf(mx, dmv[j]);
      }
      mx = fmaxf(mx, __shfl_xor(mx, 1));
      mx = fmaxf(mx, __shfl_xor(mx, 2));
      mx = fmaxf(mx, __shfl_xor(mx, 4));
      mx = fmaxf(mx, __shfl_xor(mx, 8));
      const float mold = sM[ti*4+i];
      const float mnew = fmaxf(mold, mx);
      const float al = (mnew == -INFINITY) ? 0.f : expf(mold - mnew);
      alpha_[i] = al;
      float sv[4];
      float rs = 0.f;
#pragma unroll
      for (int j=0;j<4;j++){
        const float w = (dmv[j] == -INFINITY) ? 0.f : expf(dmv[j] - mnew);
        sv[j] = qk[i][j]*w;
        rs += sv[j];
      }
      rs += __shfl_xor(rs, 1);
      rs += __shfl_xor(rs, 2);
      rs += __shfl_xor(rs, 4);
      rs += __shfl_xor(rs, 8);
      if (si == 0) { sM[ti*4+i] = mnew; sSum[ti*4+i] = sSum[ti*4+i]*al + rs; }
      sS[(ti*4+i)*33 + si*2]     = packbf(sv[0], sv[1]);
      sS[(ti*4+i)*33 + si*2 + 1] = packbf(sv[2], sv[3]);
    }
    __syncthreads();

    // ---- PV: thread (ti, di=si) owns rows ti*4.., d-pairs si*4.. ----
#pragma unroll
    for (int i=0;i<4;i++)
#pragma unroll
      for (int j=0;j<4;j++){ o[i][j][0]*=alpha_[i]; o[i][j][1]*=alpha_[i]; }
    for (int s2 = 0; s2 < 32; s2++) {
      float w0[4], w1[4];
#pragma unroll
      for (int i=0;i<4;i++){
        unsigned uu = sS[(ti*4+i)*33 + s2];
        w0[i] = bflo(uu); w1[i] = bfhi(uu);
      }
#pragma unroll
      for (int j=0;j<4;j++){
        const unsigned va = sV[(2*s2)*APD + si*4+j];
        const unsigned vb = sV[(2*s2+1)*APD + si*4+j];
        const float v0x = bflo(va), v0y = bfhi(va);
        const float v1x = bflo(vb), v1y = bfhi(vb);
#pragma unroll
        for (int i=0;i<4;i++){
          o[i][j][0] += w0[i]*v0x + w1[i]*v1x;
          o[i][j][1] += w0[i]*v0y + w1[i]*v1y;
        }
      }
    }
    __syncthreads();
  }

  // ---- epilogue: h = O / max(|ssum|, exp(-m)) ----
#pragma unroll
  for (int i=0;i<4;i++){
    const int tg = t0 + ti*4 + i;
    if (tg >= T_) continue;
    const float mf = sM[ti*4+i], ssm = sSum[ti*4+i];
    const float inv = 1.f / fmaxf(fabsf(ssm), expf(-mf));
    float* op = hatt + ((long)(b*T_+tg))*DI_ + hd*DHI_ + si*8;
#pragma unroll
    for (int j=0;j<4;j++){
      op[j*2]   = o[i][j][0]*inv;
      op[j*2+1] = o[i][j][1]*inv;
    }
  }
}

// ---------------- head_norm(dh=128)*gn + skip*xc, then *silu(z) ----------------
__global__ __launch_bounds__(128) void hn_mlstm(
    const float* __restrict__ hatt, const void* __restrict__ gn, long offG,
    const void* __restrict__ skip, long offSk, const float* __restrict__ xc,
    const float* __restrict__ u, float* __restrict__ gin,
    const int* __restrict__ dflag)
{
  const int isbf = *dflag;
  const int blk = blockIdx.x;
  const int bt = blk >> 3, hd = blk & 7;
  const int e = threadIdx.x;
  const int j = hd*DHI_ + e;
  const long idx = (long)bt*DI_ + j;
  const float x = hatt[idx];
  __shared__ float r1[128], r2[128];
  r1[e]=x; r2[e]=x*x; __syncthreads();
  for (int o=64;o>0;o>>=1){ if(e<o){r1[e]+=r1[e+o]; r2[e]+=r2[e+o];} __syncthreads(); }
  const float mu = r1[0]*(1.f/128.f);
  const float var = r2[0]*(1.f/128.f)-mu*mu;
  const float y = (x-mu)*rsqrtf(var+EPS_)*ldin(gn, offG+j, isbf) + ldin(skip, offSk+j, isbf)*xc[idx];
  const float z = u[(long)bt*2048 + DI_ + j];
  gin[idx] = y * siluf(z);
}

// ---------------- final transpose to output ----------------
__global__ void out_transpose(const float* __restrict__ hp, void* __restrict__ out,
                              const int* __restrict__ dflag)
{
  const int isbf = *dflag;
  const int tid = threadIdx.x;
  if (tid < B_*6) {
    const int b = tid / 6, hd = tid % 6;
    const float v = hp[hd*B_ + b];
    if (isbf) ((bf16*)out)[tid] = __float2bfloat16(v);
    else      ((float*)out)[tid] = v;
  }
}

extern "C" void kernel_launch(void* const* d_in, const int* in_sizes, int n_in,
                              void* d_out, int out_size, void* d_ws, size_t ws_size,
                              hipStream_t stream)
{
  (void)in_sizes; (void)n_in; (void)out_size;
  const void* x        = d_in[0];
  const void* w_in     = d_in[1];
  const void* b_in     = d_in[2];
  const void* ln_in_s  = d_in[3];
  const void* ln_in_b  = d_in[4];
  const void* s_ln_s   = d_in[5];
  const void* s_ln_b   = d_in[6];
  const void* s_conv_w = d_in[7];
  const void* s_conv_b = d_in[8];
  const void* s_wg     = d_in[9];
  const void* s_rg     = d_in[10];
  const void* s_bg     = d_in[11];
  const void* s_gn     = d_in[12];
  const void* s_ffln_s = d_in[13];
  const void* s_ffln_b = d_in[14];
  const void* s_ff_w1  = d_in[15];
  const void* s_ff_w2  = d_in[16];
  const void* m_ln_s   = d_in[17];
  const void* m_ln_b   = d_in[18];
  const void* m_w_up   = d_in[19];
  const void* m_conv_w = d_in[20];
  const void* m_conv_b = d_in[21];
  const void* m_wq     = d_in[22];
  const void* m_wk     = d_in[23];
  const void* m_wv     = d_in[24];
  const void* m_w_if   = d_in[25];
  const void* m_b_if   = d_in[26];
  const void* m_skip   = d_in[27];
  const void* m_gn     = d_in[28];
  const void* m_w_down = d_in[29];
  const void* post_ln_s= d_in[30];
  const void* post_ln_b= d_in[31];
  const void* hw1      = d_in[32];
  const void* hb1      = d_in[33];
  const void* hw2      = d_in[34];
  const void* hb2      = d_in[35];
  const void* hw3      = d_in[36];
  const void* hb3      = d_in[37];

  float* W   = (float*)d_ws;
  float* h   = W;                  // BT*D
  float* xn  = W + 4128768L;       // BT*D
  float* xc  = W + 8257536L;       // BT*DI
  float* u   = W + 16515072L;      // 4*BT*D (sLSTM gates / mLSTM up-proj / FF u)
  float* q   = W + 33030144L;      // BT*DI (also hs, ffg, hatt in-place, gin)
  float* k   = W + 41287680L;      // BT*DI
  float* v   = W + 49545216L;      // BT*DI
  float* g16 = W + 57802752L;      // BT*16
  float* cfb = W + 57931776L;      // B*NH*T
  float* lib = W + 57996288L;      // B*NH*T
  float* last= W + 58060800L;      // 32*512
  float* ha1 = W + 58077184L;      // 6*32*256
  float* ha2 = W + 58126336L;      // 6*32*128
  float* hp  = W + 58150912L;      // 6*32
  int*   dfl = (int*)(W + 58151168L);
  unsigned short* wtBase = (unsigned short*)(W + 58151424L);

  // bf16 W^T pool offsets (ushort elements)
  unsigned short* wtWg = wtBase;                 // 16 x 512x512
  unsigned short* wtF1 = wtBase + 4194304L;      // 4 x 1364x512
  unsigned short* wtF2 = wtBase + 6987776L;      // 4 x 512x682
  unsigned short* wtUp = wtBase + 8384512L;      // 3 x 2048x512
  unsigned short* wtQ  = wtBase + 11530240L;     // 24 x 128x128
  unsigned short* wtK  = wtBase + 11923456L;
  unsigned short* wtV  = wtBase + 12316672L;
  unsigned short* wtDn = wtBase + 12709888L;     // 3 x 512x1024  (end 14282752)

  const bool useMfma = ws_size >= (size_t)(58151424L + 7141376L) * 4u;
  const float kscale = 0.08838834764831845f; // 1/sqrt(128)

  detect_dtype<<<1, 64, 0, stream>>>((const unsigned*)ln_in_s, dfl);

  if (useMfma) {
    wt_transpose<<<dim3(16,16,16),256,0,stream>>>(s_wg, 0, 262144L, 512, 512, wtWg, 262144L, dfl);
    wt_transpose<<<dim3(43,16,4),256,0,stream>>>(s_ff_w1, 0, 698368L, 512, 1364, wtF1, 698368L, dfl);
    wt_transpose<<<dim3(16,22,4),256,0,stream>>>(s_ff_w2, 0, 349184L, 682, 512, wtF2, 349184L, dfl);
    wt_transpose<<<dim3(64,16,3),256,0,stream>>>(m_w_up, 0, 1048576L, 512, 2048, wtUp, 1048576L, dfl);
    wt_transpose<<<dim3(4,4,24),256,0,stream>>>(m_wq, 0, 16384L, 128, 128, wtQ, 16384L, dfl);
    wt_transpose<<<dim3(4,4,24),256,0,stream>>>(m_wk, 0, 16384L, 128, 128, wtK, 16384L, dfl);
    wt_transpose<<<dim3(4,4,24),256,0,stream>>>(m_wv, 0, 16384L, 128, 128, wtV, 16384L, dfl);
    wt_transpose<<<dim3(16,32,3),256,0,stream>>>(m_w_down, 0, 524288L, 1024, 512, wtDn, 524288L, dfl);
  }

  ln_proj<<<BT_, 256, 0, stream>>>(x, w_in, b_in, ln_in_s, ln_in_b, h, dfl);

  int si = 0, mi = 0;
  for (int blk = 0; blk < 7; blk++) {
    if ((blk & 1) == 0) {
      // ---- sLSTM block ----
      ln_rows<<<BT_,256,0,stream>>>(h, 512L, s_ln_s, (long)si*512, s_ln_b, (long)si*512, xn, dfl);
      {
        long tot = (long)BT_*512; int g = (int)((tot+255)/256);
        conv_silu<<<g,256,0,stream>>>(xn, 512, s_conv_w, (long)si*4*512, s_conv_b, (long)si*512, xc, 512, dfl);
      }
      for (int g = 0; g < 4; g++) {
        const float* Ain = (g < 2) ? xc : xn;  // i,f from conv; z,o from normed x
        if (useMfma)
          gemm_mfma<<<dim3(4,63,1),256,0,stream>>>(Ain, wtWg + (long)(si*4+g)*262144L,
              s_bg, (long)(si*4+g)*512, u + (long)g*BT_*512,
              512, 512, 512, 512, 0,0,0,0, 1.f, 1, dfl);
        else
          gemm_f32b<<<dim3(8,126,1),256,0,stream>>>(Ain, s_wg, ((long)(si*4+g))*512*512,
              s_bg, (long)(si*4+g)*512, u + (long)g*BT_*512,
              BT_, 512, 512, 512, 512, 512, 0,0,0,0, 1.f, 1, dfl);
      }
      slstm_scan<<<256,256,0,stream>>>(u, s_rg, (long)si*4*8*64*64, q /*hs*/, dfl);
      hn_add<<<BT_*8,64,0,stream>>>(q, s_gn, (long)si*512, h, dfl);
      // ---- FF block ----
      ln_rows<<<BT_,256,0,stream>>>(h, 512L, s_ffln_s, (long)si*512, s_ffln_b, (long)si*512, xn, dfl);
      if (useMfma)
        gemm_mfma<<<dim3(11,63,1),256,0,stream>>>(xn, wtF1 + (long)si*698368L, nullptr, 0,
              u, 1364, 512, 512, 1364, 0,0,0,0, 1.f, 0, dfl);
      else
        gemm_f32b<<<dim3(22,126,1),256,0,stream>>>(xn, s_ff_w1, (long)si*512*1364, nullptr, 0,
              u, BT_, 1364, 512, 512, 1364, 1364, 0,0,0,0, 1.f, 0, dfl);
      {
        long tot = (long)BT_*FF_; int g = (int)((tot+255)/256);
        ffgate<<<g,256,0,stream>>>(u, q /*ffg*/);
      }
      if (useMfma)
        gemm_mfma<<<dim3(4,63,1),256,0,stream>>>(q, wtF2 + (long)si*349184L, nullptr, 0,
              h, 512, 682, 682, 512, 0,0,0,0, 1.f, 2, dfl);
      else
        gemm_f32b<<<dim3(8,126,1),256,0,stream>>>(q, s_ff_w2, (long)si*682*512, nullptr, 0,
              h, BT_, 512, 682, 682, 512, 512, 0,0,0,0, 1.f, 2, dfl);
      si++;
    } else {
      // ---- mLSTM block ----
      ln_rows<<<BT_,256,0,stream>>>(h, 512L, m_ln_s, (long)mi*512, m_ln_b, (long)mi*512, xn, dfl);
      if (useMfma)
        gemm_mfma<<<dim3(16,63,1),256,0,stream>>>(xn, wtUp + (long)mi*1048576L, nullptr, 0,
              u, 2048, 512, 512, 2048, 0,0,0,0, 1.f, 0, dfl);
      else
        gemm_f32b<<<dim3(32,126,1),256,0,stream>>>(xn, m_w_up, (long)mi*512*2048, nullptr, 0,
              u, BT_, 2048, 512, 512, 2048, 2048, 0,0,0,0, 1.f, 0, dfl);
      {
        long tot = (long)BT_*1024; int g = (int)((tot+255)/256);
        conv_silu<<<g,256,0,stream>>>(u, 2048, m_conv_w, (long)mi*4*1024, m_conv_b, (long)mi*1024, xc, 1024, dfl);
      }
      if (useMfma) {
        gemm_mfma<<<dim3(1,63,8),256,0,stream>>>(xc, wtQ + (long)mi*131072L, nullptr, 0,
              q, 128, 128, 1024, 1024, 128, 16384, 128, 0, 1.f, 0, dfl);
        gemm_mfma<<<dim3(1,63,8),256,0,stream>>>(xc, wtK + (long)mi*131072L, nullptr, 0,
              k, 128, 128, 1024, 1024, 128, 16384, 128, 0, kscale, 0, dfl);
        gemm_mfma<<<dim3(1,63,8),256,0,stream>>>(u, wtV + (long)mi*131072L, nullptr, 0,
              v, 128, 128, 2048, 1024, 128, 16384, 128, 0, 1.f, 0, dfl);
      } else {
        gemm_f32b<<<dim3(2,126,8),256,0,stream>>>(xc, m_wq, (long)mi*8*128*128, nullptr, 0,
              q, BT_, 128, 128, 1024, 128, 1024, 128, 16384, 128, 0, 1.f, 0, dfl);
        gemm_f32b<<<dim3(2,126,8),256,0,stream>>>(xc, m_wk, (long)mi*8*128*128, nullptr, 0,
              k, BT_, 128, 128, 1024, 128, 1024, 128, 16384, 128, 0, kscale, 0, dfl);
        gemm_f32b<<<dim3(2,126,8),256,0,stream>>>(u, m_wv, (long)mi*8*128*128, nullptr, 0,
              v, BT_, 128, 128, 2048, 128, 1024, 128, 16384, 128, 0, 1.f, 0, dfl);
      }
      gemm_f32b<<<dim3(1,126,1),256,0,stream>>>(xc, m_w_if, (long)mi*1024*16, m_b_if, (long)mi*16,
            g16, BT_, 16, 1024, 1024, 16, 16, 0,0,0,0, 1.f, 1, dfl);
      mlstm_cf<<<256,256,0,stream>>>(g16, cfb, lib);
      attn_flash<<<dim3(4,256),256,0,stream>>>(q, k, v, cfb, lib, q /*hatt in-place*/);
      hn_mlstm<<<BT_*8,128,0,stream>>>(q, m_gn, (long)mi*1024, m_skip, (long)mi*1024, xc, u, q, dfl);
      if (useMfma)
        gemm_mfma<<<dim3(4,63,1),256,0,stream>>>(q, wtDn + (long)mi*524288L, nullptr, 0,
              h, 512, 1024, 1024, 512, 0,0,0,0, 1.f, 2, dfl);
      else
        gemm_f32b<<<dim3(8,126,1),256,0,stream>>>(q, m_w_down, (long)mi*1024*512, nullptr, 0,
              h, BT_, 512, 1024, 1024, 512, 512, 0,0,0,0, 1.f, 2, dfl);
      mi++;
    }
  }

  // post-LN on last timestep rows only
  ln_rows<<<B_,256,0,stream>>>(h + (long)(T_-1)*512, (long)T_*512, post_ln_s, 0, post_ln_b, 0, last, dfl);

  // 6 prediction heads, batched over grid.z
  gemm_f32b<<<dim3(4,1,6),256,0,stream>>>(last, hw1, 0, hb1, 0, ha1, 32, 256, 512, 512, 256, 256,
        0, 512L*256, 32L*256, 256, 1.f, 1|4, dfl);
  gemm_f32b<<<dim3(2,1,6),256,0,stream>>>(ha1, hw2, 0, hb2, 0, ha2, 32, 128, 256, 256, 128, 128,
        32L*256, 256L*128, 32L*128, 128, 1.f, 1|4, dfl);
  gemm_f32b<<<dim3(1,1,6),256,0,stream>>>(ha2, hw3, 0, hb3, 0, hp, 32, 1, 128, 128, 1, 1,
        32L*128, 128L, 32L, 1, 1.f, 1, dfl);
  out_transpose<<<1,256,0,stream>>>(hp, d_out, dfl);
}

// Round 5
// 4508.210 us; speedup vs baseline: 2.0917x; 1.6536x over previous
//
#include <hip/hip_runtime.h>
#include <hip/hip_bf16.h>
#include <cmath>

typedef __hip_bfloat16 bf16;

#define B_   32
#define T_   252
#define F_   8
#define D_   512
#define NH_  8
#define DH_  64
#define DI_  1024
#define DHI_ 128
#define FF_  682
#define FF2_ 1364
#define FFP_ 704
#define BT_  (B_*T_)
#define EPS_ 1e-5f

typedef __attribute__((ext_vector_type(8))) short short8;
typedef __attribute__((ext_vector_type(4))) float floatx4;

__device__ __forceinline__ float b2f(bf16 v){ return __bfloat162float(v); }
__device__ __forceinline__ float siluf(float x){ return x/(1.f+expf(-x)); }
__device__ __forceinline__ float geluf(float x){
  float x3 = x*x*x;
  return 0.5f*x*(1.f+tanhf(0.7978845608028654f*(x+0.044715f*x3)));
}
__device__ __forceinline__ float ldin(const void* p, long i, int isbf){
  return isbf ? __bfloat162float(((const bf16*)p)[i]) : ((const float*)p)[i];
}
__device__ __forceinline__ unsigned short f2bu(float f){
  bf16 h = __float2bfloat16(f);
  return *(reinterpret_cast<unsigned short*>(&h));
}
__device__ __forceinline__ void split2(float v, unsigned short& h, unsigned short& l){
  bf16 hb = __float2bfloat16(v);
  h = *(reinterpret_cast<unsigned short*>(&hb));
  float r = v - __bfloat162float(hb);
  bf16 lb = __float2bfloat16(r);
  l = *(reinterpret_cast<unsigned short*>(&lb));
}
__device__ __forceinline__ unsigned packbf(float x, float y){
  return (unsigned)f2bu(x) | ((unsigned)f2bu(y) << 16);
}
__device__ __forceinline__ float bflo(unsigned u_){
  return __uint_as_float((u_ & 0xFFFFu) << 16);
}
__device__ __forceinline__ float bfhi(unsigned u_){
  return __uint_as_float(u_ & 0xFFFF0000u);
}

__global__ void detect_dtype(const unsigned* __restrict__ probe, int* __restrict__ flag)
{
  if (threadIdx.x == 0) *flag = (*probe == 0x3F803F80u) ? 1 : 0;
}

// ---- weight transpose + hi/lo bf16 split: in [K][N] -> planes [N][outK] (outK>=K zero-pad) ----
__global__ __launch_bounds__(256) void wt_transpose2(
    const void* __restrict__ in, long inOff, long inStride, int K, int N, int outK,
    unsigned short* __restrict__ outHi, unsigned short* __restrict__ outLo,
    long outStride, const int* __restrict__ dflag)
{
  const int isbf = *dflag;
  const int bz = blockIdx.z;
  const long base = inOff + (long)bz*inStride;
  unsigned short* oh = outHi + (long)bz*outStride;
  unsigned short* ol = outLo ? outLo + (long)bz*outStride : nullptr;
  __shared__ float tile[32][33];
  const int k0 = blockIdx.y*32, n0 = blockIdx.x*32;
  const int tn = threadIdx.x & 31, tk = threadIdx.x >> 5;
#pragma unroll
  for (int i=0;i<4;i++){
    int kk = tk + i*8;
    float v = 0.f;
    if (k0+kk < K && n0+tn < N) v = ldin(in, base + (long)(k0+kk)*N + n0+tn, isbf);
    tile[kk][tn] = v;
  }
  __syncthreads();
#pragma unroll
  for (int i=0;i<4;i++){
    int nn = tk + i*8;
    if (n0+nn < N && k0+tn < outK){
      unsigned short h, l;
      split2(tile[tn][nn], h, l);
      oh[(long)(n0+nn)*outK + k0+tn] = h;
      if (ol) ol[(long)(n0+nn)*outK + k0+tn] = l;
    }
  }
}

// ---- split-bf16 MFMA GEMM: C = alpha*(A@B) [+bias] [+C] ----
// 64x64 tile, BK=64, 4 waves each computing a 32x32 quadrant.
// A fp32, split to hi/lo in staging. B planes bf16 [N][K] k-contig.
// zSplit: blocks with blockIdx.z < zSplit use A0, else A1; then A += bz*strideA.
// flags: 1=bias, 2=accumulate, 8=store C as packed bf16 (ushort)
__global__ __launch_bounds__(256) void gemm_split(
    const float* __restrict__ A0, const float* __restrict__ A1, int zSplit, long strideA,
    const unsigned short* __restrict__ Bhi, const unsigned short* __restrict__ Blo,
    const void* __restrict__ bias, long offBias, float* __restrict__ C,
    int N, int K, int lda, int ldc,
    long strideBT, long strideC, long strideBias,
    float alpha, int flags, int splitB, const int* __restrict__ dflag)
{
  const int isbf = *dflag;
  const int bz = blockIdx.z;
  const float* A = ((bz < zSplit) ? A0 : A1) + (long)bz*strideA;
  const unsigned short* bhp = Bhi + (long)bz*strideBT;
  const unsigned short* blp = Blo + (long)bz*strideBT;
  const long cBase = (long)bz*strideC;
  const long bBias = offBias + (long)bz*strideBias;

  __shared__ unsigned short aH[64*72], aL[64*72], bH[64*72], bL[64*72];
  const int tid = threadIdx.x;
  const int wid = tid >> 6, lane = tid & 63;
  const int wm = (wid >> 1)*32, wn = (wid & 1)*32;
  const int m0 = blockIdx.y*64, n0 = blockIdx.x*64;
  const int lr = lane & 15, lq = lane >> 4;

  floatx4 acc[2][2];
#pragma unroll
  for (int mi=0;mi<2;mi++)
#pragma unroll
    for (int ni=0;ni<2;ni++)
#pragma unroll
      for (int r=0;r<4;r++) acc[mi][ni][r] = 0.f;

  const int sRow = tid >> 2;        // 0..63
  const int sSeg = (tid & 3)*16;    // 0,16,32,48

  for (int k0 = 0; k0 < K; k0 += 64) {
    // A stage: fp32 -> (hi, lo) bf16 planes
    {
      const float* ap = A + (long)(m0 + sRow)*lda + k0 + sSeg;
#pragma unroll
      for (int c=0;c<4;c++){
        const float4 v = *(const float4*)(ap + c*4);
        unsigned short h0,h1,h2,h3,l0,l1,l2,l3;
        split2(v.x,h0,l0); split2(v.y,h1,l1); split2(v.z,h2,l2); split2(v.w,h3,l3);
        uint2 ph, pl;
        ph.x = (unsigned)h0 | ((unsigned)h1<<16); ph.y = (unsigned)h2 | ((unsigned)h3<<16);
        pl.x = (unsigned)l0 | ((unsigned)l1<<16); pl.y = (unsigned)l2 | ((unsigned)l3<<16);
        *(uint2*)&aH[sRow*72 + sSeg + c*4] = ph;
        *(uint2*)&aL[sRow*72 + sSeg + c*4] = pl;
      }
    }
    // B stage (already bf16, k-contig)
    {
      const int gn = n0 + sRow;
      const bool nv = gn < N;
      const long bo = (long)gn*K + k0 + sSeg;
      uint4 z4; z4.x=z4.y=z4.z=z4.w=0;
      uint4 h0 = nv ? *(const uint4*)(bhp + bo)     : z4;
      uint4 h1 = nv ? *(const uint4*)(bhp + bo + 8) : z4;
      *(uint4*)&bH[sRow*72 + sSeg]     = h0;
      *(uint4*)&bH[sRow*72 + sSeg + 8] = h1;
      if (splitB){
        uint4 l0_ = nv ? *(const uint4*)(blp + bo)     : z4;
        uint4 l1_ = nv ? *(const uint4*)(blp + bo + 8) : z4;
        *(uint4*)&bL[sRow*72 + sSeg]     = l0_;
        *(uint4*)&bL[sRow*72 + sSeg + 8] = l1_;
      }
    }
    __syncthreads();

#pragma unroll
    for (int ks=0;ks<2;ks++){
      short8 ah[2], al[2], bh_[2], bl_[2];
#pragma unroll
      for (int mi=0;mi<2;mi++){
        ah[mi] = *(const short8*)&aH[(wm+mi*16+lr)*72 + ks*32 + lq*8];
        al[mi] = *(const short8*)&aL[(wm+mi*16+lr)*72 + ks*32 + lq*8];
      }
#pragma unroll
      for (int ni=0;ni<2;ni++){
        bh_[ni] = *(const short8*)&bH[(wn+ni*16+lr)*72 + ks*32 + lq*8];
        if (splitB) bl_[ni] = *(const short8*)&bL[(wn+ni*16+lr)*72 + ks*32 + lq*8];
      }
#pragma unroll
      for (int mi=0;mi<2;mi++)
#pragma unroll
        for (int ni=0;ni<2;ni++){
          acc[mi][ni] = __builtin_amdgcn_mfma_f32_16x16x32_bf16(al[mi], bh_[ni], acc[mi][ni], 0,0,0);
          if (splitB)
            acc[mi][ni] = __builtin_amdgcn_mfma_f32_16x16x32_bf16(ah[mi], bl_[ni], acc[mi][ni], 0,0,0);
          acc[mi][ni] = __builtin_amdgcn_mfma_f32_16x16x32_bf16(ah[mi], bh_[ni], acc[mi][ni], 0,0,0);
        }
    }
    __syncthreads();
  }

  // epilogue: C/D layout col=lane&15, row=lq*4+rr (m89-verified)
#pragma unroll
  for (int mi=0;mi<2;mi++){
#pragma unroll
    for (int ni=0;ni<2;ni++){
      const int gn = n0 + wn + ni*16 + lr;
      if (gn >= N) continue;
      const float bv = (flags & 1) ? ldin(bias, bBias + gn, isbf) : 0.f;
#pragma unroll
      for (int rr=0;rr<4;rr++){
        const int gm = m0 + wm + mi*16 + lq*4 + rr;
        float vv = acc[mi][ni][rr]*alpha + bv;
        const long idx = cBase + (long)gm*ldc + gn;
        if (flags & 8) {
          ((unsigned short*)C)[idx] = f2bu(vv);
        } else {
          if (flags & 2) vv += C[idx];
          C[idx] = vv;
        }
      }
    }
  }
}

// ---------------- input projection + layernorm ----------------
__global__ __launch_bounds__(256) void ln_proj(
    const void* __restrict__ x, const void* __restrict__ w,
    const void* __restrict__ bb, const void* __restrict__ s,
    const void* __restrict__ b, float* __restrict__ out,
    const int* __restrict__ dflag)
{
  const int isbf = *dflag;
  const int r = blockIdx.x;
  const int tid = threadIdx.x;
  float xr[8];
#pragma unroll
  for (int f = 0; f < 8; f++) xr[f] = ldin(x, (long)r*8+f, isbf);
  float vv[2];
#pragma unroll
  for (int i2 = 0; i2 < 2; i2++) {
    const int j = tid + i2*256;
    float a = ldin(bb, j, isbf);
#pragma unroll
    for (int f = 0; f < 8; f++) a += xr[f]*ldin(w, f*512+j, isbf);
    vv[i2] = a;
  }
  __shared__ float r1[256], r2[256];
  r1[tid] = vv[0]+vv[1]; r2[tid] = vv[0]*vv[0]+vv[1]*vv[1];
  __syncthreads();
  for (int o = 128; o > 0; o >>= 1) {
    if (tid < o) { r1[tid]+=r1[tid+o]; r2[tid]+=r2[tid+o]; }
    __syncthreads();
  }
  const float mu = r1[0]*(1.f/512.f);
  const float var = r2[0]*(1.f/512.f)-mu*mu;
  const float rstd = rsqrtf(var+EPS_);
  float* orow = out + (long)r*512;
#pragma unroll
  for (int i2 = 0; i2 < 2; i2++) {
    const int j = tid + i2*256;
    orow[j] = (vv[i2]-mu)*rstd*ldin(s, j, isbf) + ldin(b, j, isbf);
  }
}

// ---------------- layernorm over 512-elem rows ----------------
__global__ __launch_bounds__(256) void ln_rows(
    const float* __restrict__ in, long rowStride,
    const void* __restrict__ s, long offS,
    const void* __restrict__ b, long offB,
    float* __restrict__ out, const int* __restrict__ dflag)
{
  const int isbf = *dflag;
  const long r = blockIdx.x;
  const int tid = threadIdx.x;
  const float* xr = in + r*rowStride;
  const float v0 = xr[tid], v1 = xr[tid+256];
  __shared__ float r1[256], r2[256];
  r1[tid] = v0+v1; r2[tid] = v0*v0+v1*v1;
  __syncthreads();
  for (int o = 128; o > 0; o >>= 1) {
    if (tid < o) { r1[tid]+=r1[tid+o]; r2[tid]+=r2[tid+o]; }
    __syncthreads();
  }
  const float mu = r1[0]*(1.f/512.f);
  const float var = r2[0]*(1.f/512.f)-mu*mu;
  const float rstd = rsqrtf(var+EPS_);
  float* orow = out + r*(long)D_;
  orow[tid]     = (v0-mu)*rstd*ldin(s, offS+tid, isbf)     + ldin(b, offB+tid, isbf);
  orow[tid+256] = (v1-mu)*rstd*ldin(s, offS+tid+256, isbf) + ldin(b, offB+tid+256, isbf);
}

// ---------------- causal conv(K=4) + silu ----------------
__global__ void conv_silu(const float* __restrict__ in, int inStride,
                          const void* __restrict__ w, long offW,
                          const void* __restrict__ bias, long offBias,
                          float* __restrict__ out, int Dc,
                          const int* __restrict__ dflag)
{
  const int isbf = *dflag;
  const long total = (long)BT_ * Dc;
  for (long idx = (long)blockIdx.x*256 + threadIdx.x; idx < total;
       idx += (long)gridDim.x*256) {
    const int d = (int)(idx % Dc);
    const long bt = idx / Dc;
    const int b = (int)(bt / T_), t = (int)(bt % T_);
    float a = ldin(bias, offBias + d, isbf);
#pragma unroll
    for (int kk = 0; kk < 4; kk++) {
      const int ts = t - 3 + kk;
      if (ts >= 0) a += ldin(w, offW + kk*Dc + d, isbf) * in[((long)(b*T_+ts))*inStride + d];
    }
    out[idx] = siluf(a);
  }
}

// ---------------- fallback SIMT GEMM ----------------
// flags: 1=bias, 2=accumulate, 4=gelu, 8=store bf16
__global__ __launch_bounds__(256) void gemm_f32b(
    const float* __restrict__ A, const void* __restrict__ Bw, long offB,
    const void* __restrict__ bias, long offBias, float* __restrict__ C,
    int M, int N, int K, int lda, int ldb, int ldc,
    long strideA, long strideB, long strideC, long strideBias,
    float alpha, int flags, const int* __restrict__ dflag)
{
  const int isbf = *dflag;
  const int bz = blockIdx.z;
  A  += (long)bz * strideA;
  const long bB = offB + (long)bz * strideB;
  const long cBase = (long)bz * strideC;
  const long bBias = offBias + (long)bz * strideBias;
  __shared__ float sA[16][68];
  __shared__ float sB[16][64];
  const int tid = threadIdx.x;
  const int tx = tid & 15, ty = tid >> 4;
  const int m0 = blockIdx.y * 64, n0 = blockIdx.x * 64;
  float acc[4][4];
#pragma unroll
  for (int i=0;i<4;i++)
#pragma unroll
    for (int j=0;j<4;j++) acc[i][j]=0.f;

  for (int k0 = 0; k0 < K; k0 += 16) {
#pragma unroll
    for (int r = 0; r < 4; r++) {
      int lin = tid + r*256;
      int kk = lin & 15, m = lin >> 4;
      int gm = m0 + m, gk = k0 + kk;
      sA[kk][m] = (gm < M && gk < K) ? A[(long)gm*lda + gk] : 0.f;
    }
#pragma unroll
    for (int r = 0; r < 4; r++) {
      int lin = tid + r*256;
      int nn = lin & 63, kk = lin >> 6;
      int gn = n0 + nn, gk = k0 + kk;
      sB[kk][nn] = (gn < N && gk < K) ? ldin(Bw, bB + (long)gk*ldb + gn, isbf) : 0.f;
    }
    __syncthreads();
#pragma unroll
    for (int kk = 0; kk < 16; kk++) {
      const float4 a4 = *(const float4*)(&sA[kk][ty*4]);
      const float4 b4 = *(const float4*)(&sB[kk][tx*4]);
      float av[4] = {a4.x, a4.y, a4.z, a4.w};
      float bv[4] = {b4.x, b4.y, b4.z, b4.w};
#pragma unroll
      for (int i=0;i<4;i++)
#pragma unroll
        for (int j=0;j<4;j++) acc[i][j] += av[i]*bv[j];
    }
    __syncthreads();
  }
#pragma unroll
  for (int i=0;i<4;i++) {
    const int gm = m0 + ty*4 + i;
    if (gm >= M) continue;
#pragma unroll
    for (int j=0;j<4;j++) {
      const int gn = n0 + tx*4 + j;
      if (gn >= N) continue;
      float vv = acc[i][j]*alpha;
      if (flags & 1) vv += ldin(bias, bBias + gn, isbf);
      if (flags & 4) vv = geluf(vv);
      const long idx = cBase + (long)gm*ldc + gn;
      if (flags & 8) {
        ((unsigned short*)C)[idx] = f2bu(vv);
      } else {
        if (flags & 2) vv += C[idx];
        C[idx] = vv;
      }
    }
  }
}

// ---------------- sLSTM recurrent scan: one block per (b, head) ----------------
__global__ __launch_bounds__(256) void slstm_scan(
    const float* __restrict__ g4, const void* __restrict__ Rg, long offR,
    float* __restrict__ hs, const int* __restrict__ dflag)
{
  const int isbf = *dflag;
  const int blk = blockIdx.x;
  const int b = blk >> 3, hd = blk & 7;
  const int tid = threadIdx.x;
  const int g = tid >> 6, e = tid & 63;
  float w[64];
  {
    const long wp = offR + ((long)(g*NH_ + hd)*64)*64 + e;
#pragma unroll
    for (int d = 0; d < 64; d++) w[d] = ldin(Rg, wp + d*64, isbf);
  }
  __shared__ float hlds[64];
  __shared__ float rec[4][64];
  if (tid < 64) hlds[tid] = 0.f;
  float c = 0.f, n = 0.f, m = 0.f;
  __syncthreads();
  const long gate_base = (long)(b*T_)*D_ + hd*64 + e;
  for (int t = 0; t < T_; t++) {
    float r = 0.f;
#pragma unroll
    for (int d4 = 0; d4 < 16; d4++) {
      const float4 hv = *(const float4*)(&hlds[d4*4]);
      r += w[4*d4]*hv.x + w[4*d4+1]*hv.y + w[4*d4+2]*hv.z + w[4*d4+3]*hv.w;
    }
    r += g4[(long)g*BT_*D_ + gate_base + (long)t*D_];
    rec[g][e] = r;
    __syncthreads();
    if (tid < 64) {
      const float it = rec[0][e], ft = rec[1][e];
      const float zt = tanhf(rec[2][e]);
      const float ot = 1.f/(1.f+expf(-rec[3][e]));
      const float mn = fmaxf(ft + m, it);
      const float ig = expf(it - mn);
      const float fg = expf(ft + m - mn);
      c = fg*c + ig*zt;
      n = fg*n + ig;
      m = mn;
      const float hn = ot*c/fmaxf(n, 1e-6f);
      hlds[e] = hn;
      hs[(long)(b*T_+t)*D_ + hd*64 + e] = hn;
    }
    __syncthreads();
  }
}

// ---------------- head_norm(dh=64) * gn, accumulated into h ----------------
__global__ __launch_bounds__(64) void hn_add(
    const float* __restrict__ hs, const void* __restrict__ gn, long offG,
    float* __restrict__ h, const int* __restrict__ dflag)
{
  const int isbf = *dflag;
  const int blk = blockIdx.x;
  const int bt = blk >> 3, hd = blk & 7;
  const int e = threadIdx.x;
  const long idx = (long)bt*D_ + hd*64 + e;
  const float x = hs[idx];
  float s1 = x, s2 = x*x;
#pragma unroll
  for (int o = 32; o > 0; o >>= 1) { s1 += __shfl_xor(s1, o); s2 += __shfl_xor(s2, o); }
  const float mu = s1*(1.f/64.f);
  const float var = s2*(1.f/64.f) - mu*mu;
  const float y = (x-mu)*rsqrtf(var+EPS_)*ldin(gn, offG + hd*64+e, isbf);
  h[idx] += y;
}

// ---------------- FF gating: gelu(g)*up, written with 704 stride (zero pad) ----------------
__global__ void ffgate(const float* __restrict__ u, float* __restrict__ out)
{
  const long total = (long)BT_*FFP_;
  for (long idx = (long)blockIdx.x*256 + threadIdx.x; idx < total;
       idx += (long)gridDim.x*256) {
    const long m = idx / FFP_;
    const int j = (int)(idx % FFP_);
    float r = 0.f;
    if (j < FF_) {
      const float g = u[m*FF2_ + j];
      r = geluf(g) * u[m*FF2_ + FF_ + j];
    }
    out[idx] = r;
  }
}

// ---------------- mLSTM gate cumsum: one block per (b, head) ----------------
__global__ __launch_bounds__(256) void mlstm_cf(
    const float* __restrict__ g16, float* __restrict__ cf, float* __restrict__ logi)
{
  const int bh = blockIdx.x;
  const int b = bh >> 3, hd = bh & 7;
  const int tid = threadIdx.x;
  __shared__ float slf[T_];
  if (tid < T_) {
    const float gf = g16[(long)(b*T_+tid)*16 + 8 + hd];
    const float ls = (gf >= 0.f) ? -log1pf(expf(-gf)) : (gf - log1pf(expf(gf)));
    slf[tid] = ls;
    logi[(long)bh*T_ + tid] = g16[(long)(b*T_+tid)*16 + hd];
  }
  __syncthreads();
  if (tid == 0) {
    float a = 0.f;
    for (int t = 0; t < T_; t++) { a += slf[t]; slf[t] = a; }
  }
  __syncthreads();
  if (tid < T_) cf[(long)bh*T_ + tid] = slf[tid];
}

// ---------------- flash-tiled mLSTM attention (K,V stored as packed bf16) ----------------
#define APD 67
__global__ __launch_bounds__(256) void attn_flash(
    const float* __restrict__ q, const unsigned short* __restrict__ k,
    const unsigned short* __restrict__ v, const float* __restrict__ cf,
    const float* __restrict__ li, float* __restrict__ hatt)
{
  const int tt = blockIdx.x, bh = blockIdx.y;
  const int b = bh >> 3, hd = bh & 7;
  const int t0 = tt*64;
  const int tid = threadIdx.x;
  const int ti = tid >> 4, si = tid & 15;

  __shared__ unsigned sQ[64*APD];
  __shared__ unsigned sK[64*APD];
  __shared__ unsigned sV[64*APD];
  __shared__ unsigned sS[64*33];
  __shared__ float sM[64], sSum[64], scft[64], scfs[64], slis[64];

  for (int idx = tid; idx < 64*64; idx += 256) {
    int r = idx >> 6, kp = idx & 63;
    int t = t0 + r;
    unsigned pk = 0;
    if (t < T_) {
      const float* qp = q + ((long)(b*T_+t))*DI_ + hd*DHI_ + kp*2;
      pk = packbf(qp[0], qp[1]);
    }
    sQ[r*APD + kp] = pk;
  }
  if (tid < 64) {
    int t = t0 + tid;
    scft[tid] = (t < T_) ? cf[(long)bh*T_ + t] : 0.f;
    sM[tid] = -INFINITY; sSum[tid] = 0.f;
  }

  float o[4][4][2];
#pragma unroll
  for (int i=0;i<4;i++)
#pragma unroll
    for (int j=0;j<4;j++){ o[i][j][0]=0.f; o[i][j][1]=0.f; }
  float alpha_[4];

  for (int st = 0; st <= tt; st++) {
    const int s0 = st*64;
    for (int idx = tid; idx < 64*64; idx += 256) {
      int r = idx >> 6, kp = idx & 63;
      int s = s0 + r;
      unsigned pkk = 0, pkv = 0;
      if (s < T_) {
        const long base = ((long)(b*T_+s))*DI_ + hd*DHI_ + kp*2;
        pkk = *(const unsigned*)&k[base];
        pkv = *(const unsigned*)&v[base];
      }
      sK[r*APD + kp] = pkk;
      sV[r*APD + kp] = pkv;
    }
    if (tid < 64) {
      int s = s0 + tid;
      scfs[tid] = (s < T_) ? cf[(long)bh*T_ + s] : 0.f;
      slis[tid] = (s < T_) ? li[(long)bh*T_ + s] : 0.f;
    }
    __syncthreads();

    float qk[4][4];
#pragma unroll
    for (int i=0;i<4;i++)
#pragma unroll
      for (int j=0;j<4;j++) qk[i][j]=0.f;
    for (int kp = 0; kp < 64; kp++) {
      float qa0[4], qa1[4], kb0[4], kb1[4];
#pragma unroll
      for (int i=0;i<4;i++){
        unsigned uu = sQ[(ti*4+i)*APD + kp];
        qa0[i] = bflo(uu); qa1[i] = bfhi(uu);
      }
#pragma unroll
      for (int j=0;j<4;j++){
        unsigned uu = sK[(si*4+j)*APD + kp];
        kb0[j] = bflo(uu); kb1[j] = bfhi(uu);
      }
#pragma unroll
      for (int i=0;i<4;i++)
#pragma unroll
        for (int j=0;j<4;j++)
          qk[i][j] += qa0[i]*kb0[j] + qa1[i]*kb1[j];
    }

#pragma unroll
    for (int i=0;i<4;i++){
      const int tg = t0 + ti*4 + i;
      float dmv[4];
      float mx = -INFINITY;
#pragma unroll
      for (int j=0;j<4;j++){
        const int sg = s0 + si*4 + j;
        const bool valid = (tg < T_) && (sg <= tg);
        dmv[j] = valid ? (scft[ti*4+i] - scfs[si*4+j] + slis[si*4+j]) : -INFINITY;
        mx = fmaxf(mx, dmv[j]);
      }
      mx = fmaxf(mx, __shfl_xor(mx, 1));
      mx = fmaxf(mx, __shfl_xor(mx, 2));
      mx = fmaxf(mx, __shfl_xor(mx, 4));
      mx = fmaxf(mx, __shfl_xor(mx, 8));
      const float mold = sM[ti*4+i];
      const float mnew = fmaxf(mold, mx);
      const float al = (mnew == -INFINITY) ? 0.f : expf(mold - mnew);
      alpha_[i] = al;
      float sv[4];
      float rs = 0.f;
#pragma unroll
      for (int j=0;j<4;j++){
        const float w = (dmv[j] == -INFINITY) ? 0.f : expf(dmv[j] - mnew);
        sv[j] = qk[i][j]*w;
        rs += sv[j];
      }
      rs += __shfl_xor(rs, 1);
      rs += __shfl_xor(rs, 2);
      rs += __shfl_xor(rs, 4);
      rs += __shfl_xor(rs, 8);
      if (si == 0) { sM[ti*4+i] = mnew; sSum[ti*4+i] = sSum[ti*4+i]*al + rs; }
      sS[(ti*4+i)*33 + si*2]     = packbf(sv[0], sv[1]);
      sS[(ti*4+i)*33 + si*2 + 1] = packbf(sv[2], sv[3]);
    }
    __syncthreads();

#pragma unroll
    for (int i=0;i<4;i++)
#pragma unroll
      for (int j=0;j<4;j++){ o[i][j][0]*=alpha_[i]; o[i][j][1]*=alpha_[i]; }
    for (int s2 = 0; s2 < 32; s2++) {
      float w0[4], w1[4];
#pragma unroll
      for (int i=0;i<4;i++){
        unsigned uu = sS[(ti*4+i)*33 + s2];
        w0[i] = bflo(uu); w1[i] = bfhi(uu);
      }
#pragma unroll
      for (int j=0;j<4;j++){
        const unsigned va = sV[(2*s2)*APD + si*4+j];
        const unsigned vb = sV[(2*s2+1)*APD + si*4+j];
        const float v0x = bflo(va), v0y = bfhi(va);
        const float v1x = bflo(vb), v1y = bfhi(vb);
#pragma unroll
        for (int i=0;i<4;i++){
          o[i][j][0] += w0[i]*v0x + w1[i]*v1x;
          o[i][j][1] += w0[i]*v0y + w1[i]*v1y;
        }
      }
    }
    __syncthreads();
  }

#pragma unroll
  for (int i=0;i<4;i++){
    const int tg = t0 + ti*4 + i;
    if (tg >= T_) continue;
    const float mf = sM[ti*4+i], ssm = sSum[ti*4+i];
    const float inv = 1.f / fmaxf(fabsf(ssm), expf(-mf));
    float* op = hatt + ((long)(b*T_+tg))*DI_ + hd*DHI_ + si*8;
#pragma unroll
    for (int j=0;j<4;j++){
      op[j*2]   = o[i][j][0]*inv;
      op[j*2+1] = o[i][j][1]*inv;
    }
  }
}

// ---------------- head_norm(dh=128)*gn + skip*xc, then *silu(z) ----------------
__global__ __launch_bounds__(128) void hn_mlstm(
    const float* __restrict__ hatt, const void* __restrict__ gn, long offG,
    const void* __restrict__ skip, long offSk, const float* __restrict__ xc,
    const float* __restrict__ u, float* __restrict__ gin,
    const int* __restrict__ dflag)
{
  const int isbf = *dflag;
  const int blk = blockIdx.x;
  const int bt = blk >> 3, hd = blk & 7;
  const int e = threadIdx.x;
  const int j = hd*DHI_ + e;
  const long idx = (long)bt*DI_ + j;
  const float x = hatt[idx];
  __shared__ float r1[128], r2[128];
  r1[e]=x; r2[e]=x*x; __syncthreads();
  for (int o=64;o>0;o>>=1){ if(e<o){r1[e]+=r1[e+o]; r2[e]+=r2[e+o];} __syncthreads(); }
  const float mu = r1[0]*(1.f/128.f);
  const float var = r2[0]*(1.f/128.f)-mu*mu;
  const float y = (x-mu)*rsqrtf(var+EPS_)*ldin(gn, offG+j, isbf) + ldin(skip, offSk+j, isbf)*xc[idx];
  const float z = u[(long)bt*2048 + DI_ + j];
  gin[idx] = y * siluf(z);
}

// ---------------- final transpose to output ----------------
__global__ void out_transpose(const float* __restrict__ hp, void* __restrict__ out,
                              const int* __restrict__ dflag)
{
  const int isbf = *dflag;
  const int tid = threadIdx.x;
  if (tid < B_*6) {
    const int b = tid / 6, hd = tid % 6;
    const float v = hp[hd*B_ + b];
    if (isbf) ((bf16*)out)[tid] = __float2bfloat16(v);
    else      ((float*)out)[tid] = v;
  }
}

extern "C" void kernel_launch(void* const* d_in, const int* in_sizes, int n_in,
                              void* d_out, int out_size, void* d_ws, size_t ws_size,
                              hipStream_t stream)
{
  (void)in_sizes; (void)n_in; (void)out_size;
  const void* x        = d_in[0];
  const void* w_in     = d_in[1];
  const void* b_in     = d_in[2];
  const void* ln_in_s  = d_in[3];
  const void* ln_in_b  = d_in[4];
  const void* s_ln_s   = d_in[5];
  const void* s_ln_b   = d_in[6];
  const void* s_conv_w = d_in[7];
  const void* s_conv_b = d_in[8];
  const void* s_wg     = d_in[9];
  const void* s_rg     = d_in[10];
  const void* s_bg     = d_in[11];
  const void* s_gn     = d_in[12];
  const void* s_ffln_s = d_in[13];
  const void* s_ffln_b = d_in[14];
  const void* s_ff_w1  = d_in[15];
  const void* s_ff_w2  = d_in[16];
  const void* m_ln_s   = d_in[17];
  const void* m_ln_b   = d_in[18];
  const void* m_w_up   = d_in[19];
  const void* m_conv_w = d_in[20];
  const void* m_conv_b = d_in[21];
  const void* m_wq     = d_in[22];
  const void* m_wk     = d_in[23];
  const void* m_wv     = d_in[24];
  const void* m_w_if   = d_in[25];
  const void* m_b_if   = d_in[26];
  const void* m_skip   = d_in[27];
  const void* m_gn     = d_in[28];
  const void* m_w_down = d_in[29];
  const void* post_ln_s= d_in[30];
  const void* post_ln_b= d_in[31];
  const void* hw1      = d_in[32];
  const void* hb1      = d_in[33];
  const void* hw2      = d_in[34];
  const void* hb2      = d_in[35];
  const void* hw3      = d_in[36];
  const void* hb3      = d_in[37];

  float* W   = (float*)d_ws;
  float* h   = W;                           // BT*D
  float* xn  = W + 4128768L;                // BT*D
  float* xc  = W + 8257536L;                // BT*DI
  float* u   = W + 16515072L;               // 4*BT*D
  float* q   = W + 33030144L;               // BT*DI fp32 (hs / ffg(704) / hatt / gin)
  unsigned short* kk_ = (unsigned short*)(W + 41287680L); // BT*DI bf16
  unsigned short* vv_ = (unsigned short*)(W + 45416448L); // BT*DI bf16
  float* g16 = W + 49545216L;               // BT*16
  float* cfb = W + 49674240L;               // B*NH*T
  float* lib = W + 49738752L;               // B*NH*T
  float* last= W + 49803264L;               // 32*512
  float* ha1 = W + 49819648L;               // 6*32*256
  float* ha2 = W + 49868800L;               // 6*32*128
  float* hp  = W + 49893376L;               // 6*32 (pad)
  int*   dfl = (int*)(W + 49893568L);

  // bf16 weight planes (hi, lo), each PLANE ushorts, k-contiguous [N][K]
  const long PLANE = 14327808L;
  unsigned short* wtHi = (unsigned short*)(W + 49893632L);
  unsigned short* wtLo = wtHi + PLANE;
  const long oWg=0, oF1=4194304L, oF2=6987776L, oUp=8429568L;
  const long oQ=11575296L, oK=11968512L, oV=12361728L, oDn=12754944L;

  const size_t needFull = (size_t)49893632L*4 + (size_t)PLANE*4;  // ~257 MB
  const size_t needMid  = (size_t)49893632L*4 + (size_t)PLANE*2;  // ~228 MB
  const int tier = (ws_size >= needFull) ? 2 : ((ws_size >= needMid) ? 1 : 0);
  const int spB = (tier == 2) ? 1 : 0;
  unsigned short* loArg = (tier == 2) ? wtLo : nullptr;

  const float kscale = 0.08838834764831845f; // 1/sqrt(128)

  detect_dtype<<<1, 64, 0, stream>>>((const unsigned*)ln_in_s, dfl);

  if (tier >= 1) {
    wt_transpose2<<<dim3(16,16,16),256,0,stream>>>(s_wg, 0, 262144L, 512, 512, 512,
        wtHi+oWg, loArg?loArg+oWg:nullptr, 262144L, dfl);
    wt_transpose2<<<dim3(43,16,4),256,0,stream>>>(s_ff_w1, 0, 698368L, 512, 1364, 512,
        wtHi+oF1, loArg?loArg+oF1:nullptr, 698368L, dfl);
    wt_transpose2<<<dim3(16,22,4),256,0,stream>>>(s_ff_w2, 0, 349184L, 682, 512, 704,
        wtHi+oF2, loArg?loArg+oF2:nullptr, 360448L, dfl);
    wt_transpose2<<<dim3(64,16,3),256,0,stream>>>(m_w_up, 0, 1048576L, 512, 2048, 512,
        wtHi+oUp, loArg?loArg+oUp:nullptr, 1048576L, dfl);
    wt_transpose2<<<dim3(4,4,24),256,0,stream>>>(m_wq, 0, 16384L, 128, 128, 128,
        wtHi+oQ, loArg?loArg+oQ:nullptr, 16384L, dfl);
    wt_transpose2<<<dim3(4,4,24),256,0,stream>>>(m_wk, 0, 16384L, 128, 128, 128,
        wtHi+oK, loArg?loArg+oK:nullptr, 16384L, dfl);
    wt_transpose2<<<dim3(4,4,24),256,0,stream>>>(m_wv, 0, 16384L, 128, 128, 128,
        wtHi+oV, loArg?loArg+oV:nullptr, 16384L, dfl);
    wt_transpose2<<<dim3(16,32,3),256,0,stream>>>(m_w_down, 0, 524288L, 1024, 512, 1024,
        wtHi+oDn, loArg?loArg+oDn:nullptr, 524288L, dfl);
  }

  ln_proj<<<BT_, 256, 0, stream>>>(x, w_in, b_in, ln_in_s, ln_in_b, h, dfl);

  int si = 0, mi = 0;
  for (int blk = 0; blk < 7; blk++) {
    if ((blk & 1) == 0) {
      // ---- sLSTM block ----
      ln_rows<<<BT_,256,0,stream>>>(h, 512L, s_ln_s, (long)si*512, s_ln_b, (long)si*512, xn, dfl);
      {
        long tot = (long)BT_*512; int g = (int)((tot+255)/256);
        conv_silu<<<g,256,0,stream>>>(xn, 512, s_conv_w, (long)si*4*512, s_conv_b, (long)si*512, xc, 512, dfl);
      }
      if (tier >= 1) {
        gemm_split<<<dim3(8,126,4),256,0,stream>>>(xc, xn, 2, 0L,
            wtHi+oWg+(long)si*4*262144L, wtLo+oWg+(long)si*4*262144L,
            s_bg, (long)si*4*512, u,
            512, 512, 512, 512, 262144L, (long)BT_*512, 512L, 1.f, 1, spB, dfl);
      } else {
        for (int g = 0; g < 4; g++) {
          const float* Ain = (g < 2) ? xc : xn;
          gemm_f32b<<<dim3(8,126,1),256,0,stream>>>(Ain, s_wg, ((long)(si*4+g))*512*512,
              s_bg, (long)(si*4+g)*512, u + (long)g*BT_*512,
              BT_, 512, 512, 512, 512, 512, 0,0,0,0, 1.f, 1, dfl);
        }
      }
      slstm_scan<<<256,256,0,stream>>>(u, s_rg, (long)si*4*8*64*64, q /*hs*/, dfl);
      hn_add<<<BT_*8,64,0,stream>>>(q, s_gn, (long)si*512, h, dfl);
      // ---- FF block ----
      ln_rows<<<BT_,256,0,stream>>>(h, 512L, s_ffln_s, (long)si*512, s_ffln_b, (long)si*512, xn, dfl);
      if (tier >= 1)
        gemm_split<<<dim3(22,126,1),256,0,stream>>>(xn, xn, 9, 0L,
            wtHi+oF1+(long)si*698368L, wtLo+oF1+(long)si*698368L, nullptr, 0,
            u, 1364, 512, 512, 1364, 0,0,0, 1.f, 0, spB, dfl);
      else
        gemm_f32b<<<dim3(22,126,1),256,0,stream>>>(xn, s_ff_w1, (long)si*512*1364, nullptr, 0,
            u, BT_, 1364, 512, 512, 1364, 1364, 0,0,0,0, 1.f, 0, dfl);
      {
        long tot = (long)BT_*FFP_; int g = (int)((tot+255)/256);
        ffgate<<<g,256,0,stream>>>(u, q /*ffg, stride 704*/);
      }
      if (tier >= 1)
        gemm_split<<<dim3(8,126,1),256,0,stream>>>(q, q, 9, 0L,
            wtHi+oF2+(long)si*360448L, wtLo+oF2+(long)si*360448L, nullptr, 0,
            h, 512, 704, 704, 512, 0,0,0, 1.f, 2, spB, dfl);
      else
        gemm_f32b<<<dim3(8,126,1),256,0,stream>>>(q, s_ff_w2, (long)si*682*512, nullptr, 0,
            h, BT_, 512, 682, 704, 512, 512, 0,0,0,0, 1.f, 2, dfl);
      si++;
    } else {
      // ---- mLSTM block ----
      ln_rows<<<BT_,256,0,stream>>>(h, 512L, m_ln_s, (long)mi*512, m_ln_b, (long)mi*512, xn, dfl);
      if (tier >= 1)
        gemm_split<<<dim3(32,126,1),256,0,stream>>>(xn, xn, 9, 0L,
            wtHi+oUp+(long)mi*1048576L, wtLo+oUp+(long)mi*1048576L, nullptr, 0,
            u, 2048, 512, 512, 2048, 0,0,0, 1.f, 0, spB, dfl);
      else
        gemm_f32b<<<dim3(32,126,1),256,0,stream>>>(xn, m_w_up, (long)mi*512*2048, nullptr, 0,
            u, BT_, 2048, 512, 512, 2048, 2048, 0,0,0,0, 1.f, 0, dfl);
      {
        long tot = (long)BT_*1024; int g = (int)((tot+255)/256);
        conv_silu<<<g,256,0,stream>>>(u, 2048, m_conv_w, (long)mi*4*1024, m_conv_b, (long)mi*1024, xc, 1024, dfl);
      }
      if (tier >= 1) {
        gemm_split<<<dim3(2,126,8),256,0,stream>>>(xc, xc, 9, 128L,
            wtHi+oQ+(long)mi*131072L, wtLo+oQ+(long)mi*131072L, nullptr, 0,
            q, 128, 128, 1024, 1024, 16384L, 128L, 0, 1.f, 0, spB, dfl);
        gemm_split<<<dim3(2,126,8),256,0,stream>>>(xc, xc, 9, 128L,
            wtHi+oK+(long)mi*131072L, wtLo+oK+(long)mi*131072L, nullptr, 0,
            (float*)kk_, 128, 128, 1024, 1024, 16384L, 128L, 0, kscale, 8, spB, dfl);
        gemm_split<<<dim3(2,126,8),256,0,stream>>>(u, u, 9, 128L,
            wtHi+oV+(long)mi*131072L, wtLo+oV+(long)mi*131072L, nullptr, 0,
            (float*)vv_, 128, 128, 2048, 1024, 16384L, 128L, 0, 1.f, 8, spB, dfl);
      } else {
        gemm_f32b<<<dim3(2,126,8),256,0,stream>>>(xc, m_wq, (long)mi*8*128*128, nullptr, 0,
            q, BT_, 128, 128, 1024, 128, 1024, 128, 16384, 128, 0, 1.f, 0, dfl);
        gemm_f32b<<<dim3(2,126,8),256,0,stream>>>(xc, m_wk, (long)mi*8*128*128, nullptr, 0,
            (float*)kk_, BT_, 128, 128, 1024, 128, 1024, 128, 16384, 128, 0, kscale, 8, dfl);
        gemm_f32b<<<dim3(2,126,8),256,0,stream>>>(u, m_wv, (long)mi*8*128*128, nullptr, 0,
            (float*)vv_, BT_, 128, 128, 2048, 128, 1024, 128, 16384, 128, 0, 1.f, 8, dfl);
      }
      gemm_f32b<<<dim3(1,126,1),256,0,stream>>>(xc, m_w_if, (long)mi*1024*16, m_b_if, (long)mi*16,
            g16, BT_, 16, 1024, 1024, 16, 16, 0,0,0,0, 1.f, 1, dfl);
      mlstm_cf<<<256,256,0,stream>>>(g16, cfb, lib);
      attn_flash<<<dim3(4,256),256,0,stream>>>(q, kk_, vv_, cfb, lib, q /*hatt in-place*/);
      hn_mlstm<<<BT_*8,128,0,stream>>>(q, m_gn, (long)mi*1024, m_skip, (long)mi*1024, xc, u, q, dfl);
      if (tier >= 1)
        gemm_split<<<dim3(8,126,1),256,0,stream>>>(q, q, 9, 0L,
            wtHi+oDn+(long)mi*524288L, wtLo+oDn+(long)mi*524288L, nullptr, 0,
            h, 512, 1024, 1024, 512, 0,0,0, 1.f, 2, spB, dfl);
      else
        gemm_f32b<<<dim3(8,126,1),256,0,stream>>>(q, m_w_down, (long)mi*1024*512, nullptr, 0,
            h, BT_, 512, 1024, 1024, 512, 512, 0,0,0,0, 1.f, 2, dfl);
      mi++;
    }
  }

  // post-LN on last timestep rows only
  ln_rows<<<B_,256,0,stream>>>(h + (long)(T_-1)*512, (long)T_*512, post_ln_s, 0, post_ln_b, 0, last, dfl);

  // 6 prediction heads, batched over grid.z (tiny; SIMT fp32)
  gemm_f32b<<<dim3(4,1,6),256,0,stream>>>(last, hw1, 0, hb1, 0, ha1, 32, 256, 512, 512, 256, 256,
        0, 512L*256, 32L*256, 256, 1.f, 1|4, dfl);
  gemm_f32b<<<dim3(2,1,6),256,0,stream>>>(ha1, hw2, 0, hb2, 0, ha2, 32, 128, 256, 256, 128, 128,
        32L*256, 256L*128, 32L*128, 128, 1.f, 1|4, dfl);
  gemm_f32b<<<dim3(1,1,6),256,0,stream>>>(ha2, hw3, 0, hb3, 0, hp, 32, 1, 128, 128, 1, 1,
        32L*128, 128L, 32L, 1, 1.f, 1, dfl);
  out_transpose<<<1,256,0,stream>>>(hp, d_out, dfl);
}

// Round 6
// 4055.454 us; speedup vs baseline: 2.3252x; 1.1116x over previous
//
#include <hip/hip_runtime.h>
#include <hip/hip_bf16.h>
#include <cmath>

typedef __hip_bfloat16 bf16;

#define B_   32
#define T_   252
#define F_   8
#define D_   512
#define NH_  8
#define DH_  64
#define DI_  1024
#define DHI_ 128
#define FF_  682
#define FF2_ 1364
#define FFP_ 704
#define BT_  (B_*T_)
#define EPS_ 1e-5f

typedef __attribute__((ext_vector_type(8))) short short8;
typedef __attribute__((ext_vector_type(4))) float floatx4;

__device__ __forceinline__ float b2f(bf16 v){ return __bfloat162float(v); }
__device__ __forceinline__ float siluf(float x){ return x/(1.f+expf(-x)); }
__device__ __forceinline__ float geluf(float x){
  float x3 = x*x*x;
  return 0.5f*x*(1.f+tanhf(0.7978845608028654f*(x+0.044715f*x3)));
}
__device__ __forceinline__ float ldin(const void* p, long i, int isbf){
  return isbf ? __bfloat162float(((const bf16*)p)[i]) : ((const float*)p)[i];
}
__device__ __forceinline__ unsigned short f2bu(float f){
  bf16 h = __float2bfloat16(f);
  return *(reinterpret_cast<unsigned short*>(&h));
}
__device__ __forceinline__ void split2(float v, unsigned short& h, unsigned short& l){
  bf16 hb = __float2bfloat16(v);
  h = *(reinterpret_cast<unsigned short*>(&hb));
  float r = v - __bfloat162float(hb);
  bf16 lb = __float2bfloat16(r);
  l = *(reinterpret_cast<unsigned short*>(&lb));
}
__device__ __forceinline__ unsigned packbf(float x, float y){
  return (unsigned)f2bu(x) | ((unsigned)f2bu(y) << 16);
}

__global__ void detect_dtype(const unsigned* __restrict__ probe, int* __restrict__ flag)
{
  if (threadIdx.x == 0) *flag = (*probe == 0x3F803F80u) ? 1 : 0;
}

// ---- weight transpose + hi/lo bf16 split: in [K][N] -> planes [N][outK] (outK>=K zero-pad) ----
__global__ __launch_bounds__(256) void wt_transpose2(
    const void* __restrict__ in, long inOff, long inStride, int K, int N, int outK,
    unsigned short* __restrict__ outHi, unsigned short* __restrict__ outLo,
    long outStride, const int* __restrict__ dflag)
{
  const int isbf = *dflag;
  const int bz = blockIdx.z;
  const long base = inOff + (long)bz*inStride;
  unsigned short* oh = outHi + (long)bz*outStride;
  unsigned short* ol = outLo ? outLo + (long)bz*outStride : nullptr;
  __shared__ float tile[32][33];
  const int k0 = blockIdx.y*32, n0 = blockIdx.x*32;
  const int tn = threadIdx.x & 31, tk = threadIdx.x >> 5;
#pragma unroll
  for (int i=0;i<4;i++){
    int kk = tk + i*8;
    float v = 0.f;
    if (k0+kk < K && n0+tn < N) v = ldin(in, base + (long)(k0+kk)*N + n0+tn, isbf);
    tile[kk][tn] = v;
  }
  __syncthreads();
#pragma unroll
  for (int i=0;i<4;i++){
    int nn = tk + i*8;
    if (n0+nn < N && k0+tn < outK){
      unsigned short h, l;
      split2(tile[tn][nn], h, l);
      oh[(long)(n0+nn)*outK + k0+tn] = h;
      if (ol) ol[(long)(n0+nn)*outK + k0+tn] = l;
    }
  }
}

// ---- split-bf16 MFMA GEMM: C = alpha*(A@B) [+bias] [+C] ----
// 64x64 tile, BK=64, 4 waves each computing a 32x32 quadrant.
// flags: 1=bias, 2=accumulate, 8=store C as packed bf16 (ushort)
__global__ __launch_bounds__(256) void gemm_split(
    const float* __restrict__ A0, const float* __restrict__ A1, int zSplit, long strideA,
    const unsigned short* __restrict__ Bhi, const unsigned short* __restrict__ Blo,
    const void* __restrict__ bias, long offBias, float* __restrict__ C,
    int N, int K, int lda, int ldc,
    long strideBT, long strideC, long strideBias,
    float alpha, int flags, int splitB, const int* __restrict__ dflag)
{
  const int isbf = *dflag;
  const int bz = blockIdx.z;
  const float* A = ((bz < zSplit) ? A0 : A1) + (long)bz*strideA;
  const unsigned short* bhp = Bhi + (long)bz*strideBT;
  const unsigned short* blp = Blo + (long)bz*strideBT;
  const long cBase = (long)bz*strideC;
  const long bBias = offBias + (long)bz*strideBias;

  __shared__ unsigned short aH[64*72], aL[64*72], bH[64*72], bL[64*72];
  const int tid = threadIdx.x;
  const int wid = tid >> 6, lane = tid & 63;
  const int wm = (wid >> 1)*32, wn = (wid & 1)*32;
  const int m0 = blockIdx.y*64, n0 = blockIdx.x*64;
  const int lr = lane & 15, lq = lane >> 4;

  floatx4 acc[2][2];
#pragma unroll
  for (int mi=0;mi<2;mi++)
#pragma unroll
    for (int ni=0;ni<2;ni++)
#pragma unroll
      for (int r=0;r<4;r++) acc[mi][ni][r] = 0.f;

  const int sRow = tid >> 2;        // 0..63
  const int sSeg = (tid & 3)*16;    // 0,16,32,48

  for (int k0 = 0; k0 < K; k0 += 64) {
    {
      const float* ap = A + (long)(m0 + sRow)*lda + k0 + sSeg;
#pragma unroll
      for (int c=0;c<4;c++){
        const float4 v = *(const float4*)(ap + c*4);
        unsigned short h0,h1,h2,h3,l0,l1,l2,l3;
        split2(v.x,h0,l0); split2(v.y,h1,l1); split2(v.z,h2,l2); split2(v.w,h3,l3);
        uint2 ph, pl;
        ph.x = (unsigned)h0 | ((unsigned)h1<<16); ph.y = (unsigned)h2 | ((unsigned)h3<<16);
        pl.x = (unsigned)l0 | ((unsigned)l1<<16); pl.y = (unsigned)l2 | ((unsigned)l3<<16);
        *(uint2*)&aH[sRow*72 + sSeg + c*4] = ph;
        *(uint2*)&aL[sRow*72 + sSeg + c*4] = pl;
      }
    }
    {
      const int gn = n0 + sRow;
      const bool nv = gn < N;
      const long bo = (long)gn*K + k0 + sSeg;
      uint4 z4; z4.x=z4.y=z4.z=z4.w=0;
      uint4 h0 = nv ? *(const uint4*)(bhp + bo)     : z4;
      uint4 h1 = nv ? *(const uint4*)(bhp + bo + 8) : z4;
      *(uint4*)&bH[sRow*72 + sSeg]     = h0;
      *(uint4*)&bH[sRow*72 + sSeg + 8] = h1;
      if (splitB){
        uint4 l0_ = nv ? *(const uint4*)(blp + bo)     : z4;
        uint4 l1_ = nv ? *(const uint4*)(blp + bo + 8) : z4;
        *(uint4*)&bL[sRow*72 + sSeg]     = l0_;
        *(uint4*)&bL[sRow*72 + sSeg + 8] = l1_;
      }
    }
    __syncthreads();

#pragma unroll
    for (int ks=0;ks<2;ks++){
      short8 ah[2], al[2], bh_[2], bl_[2];
#pragma unroll
      for (int mi=0;mi<2;mi++){
        ah[mi] = *(const short8*)&aH[(wm+mi*16+lr)*72 + ks*32 + lq*8];
        al[mi] = *(const short8*)&aL[(wm+mi*16+lr)*72 + ks*32 + lq*8];
      }
#pragma unroll
      for (int ni=0;ni<2;ni++){
        bh_[ni] = *(const short8*)&bH[(wn+ni*16+lr)*72 + ks*32 + lq*8];
        if (splitB) bl_[ni] = *(const short8*)&bL[(wn+ni*16+lr)*72 + ks*32 + lq*8];
      }
#pragma unroll
      for (int mi=0;mi<2;mi++)
#pragma unroll
        for (int ni=0;ni<2;ni++){
          acc[mi][ni] = __builtin_amdgcn_mfma_f32_16x16x32_bf16(al[mi], bh_[ni], acc[mi][ni], 0,0,0);
          if (splitB)
            acc[mi][ni] = __builtin_amdgcn_mfma_f32_16x16x32_bf16(ah[mi], bl_[ni], acc[mi][ni], 0,0,0);
          acc[mi][ni] = __builtin_amdgcn_mfma_f32_16x16x32_bf16(ah[mi], bh_[ni], acc[mi][ni], 0,0,0);
        }
    }
    __syncthreads();
  }

#pragma unroll
  for (int mi=0;mi<2;mi++){
#pragma unroll
    for (int ni=0;ni<2;ni++){
      const int gn = n0 + wn + ni*16 + lr;
      if (gn >= N) continue;
      const float bv = (flags & 1) ? ldin(bias, bBias + gn, isbf) : 0.f;
#pragma unroll
      for (int rr=0;rr<4;rr++){
        const int gm = m0 + wm + mi*16 + lq*4 + rr;
        float vv = acc[mi][ni][rr]*alpha + bv;
        const long idx = cBase + (long)gm*ldc + gn;
        if (flags & 8) {
          ((unsigned short*)C)[idx] = f2bu(vv);
        } else {
          if (flags & 2) vv += C[idx];
          C[idx] = vv;
        }
      }
    }
  }
}

// ---------------- input projection + layernorm ----------------
__global__ __launch_bounds__(256) void ln_proj(
    const void* __restrict__ x, const void* __restrict__ w,
    const void* __restrict__ bb, const void* __restrict__ s,
    const void* __restrict__ b, float* __restrict__ out,
    const int* __restrict__ dflag)
{
  const int isbf = *dflag;
  const int r = blockIdx.x;
  const int tid = threadIdx.x;
  float xr[8];
#pragma unroll
  for (int f = 0; f < 8; f++) xr[f] = ldin(x, (long)r*8+f, isbf);
  float vv[2];
#pragma unroll
  for (int i2 = 0; i2 < 2; i2++) {
    const int j = tid + i2*256;
    float a = ldin(bb, j, isbf);
#pragma unroll
    for (int f = 0; f < 8; f++) a += xr[f]*ldin(w, f*512+j, isbf);
    vv[i2] = a;
  }
  __shared__ float r1[256], r2[256];
  r1[tid] = vv[0]+vv[1]; r2[tid] = vv[0]*vv[0]+vv[1]*vv[1];
  __syncthreads();
  for (int o = 128; o > 0; o >>= 1) {
    if (tid < o) { r1[tid]+=r1[tid+o]; r2[tid]+=r2[tid+o]; }
    __syncthreads();
  }
  const float mu = r1[0]*(1.f/512.f);
  const float var = r2[0]*(1.f/512.f)-mu*mu;
  const float rstd = rsqrtf(var+EPS_);
  float* orow = out + (long)r*512;
#pragma unroll
  for (int i2 = 0; i2 < 2; i2++) {
    const int j = tid + i2*256;
    orow[j] = (vv[i2]-mu)*rstd*ldin(s, j, isbf) + ldin(b, j, isbf);
  }
}

// ---------------- layernorm over 512-elem rows ----------------
__global__ __launch_bounds__(256) void ln_rows(
    const float* __restrict__ in, long rowStride,
    const void* __restrict__ s, long offS,
    const void* __restrict__ b, long offB,
    float* __restrict__ out, const int* __restrict__ dflag)
{
  const int isbf = *dflag;
  const long r = blockIdx.x;
  const int tid = threadIdx.x;
  const float* xr = in + r*rowStride;
  const float v0 = xr[tid], v1 = xr[tid+256];
  __shared__ float r1[256], r2[256];
  r1[tid] = v0+v1; r2[tid] = v0*v0+v1*v1;
  __syncthreads();
  for (int o = 128; o > 0; o >>= 1) {
    if (tid < o) { r1[tid]+=r1[tid+o]; r2[tid]+=r2[tid+o]; }
    __syncthreads();
  }
  const float mu = r1[0]*(1.f/512.f);
  const float var = r2[0]*(1.f/512.f)-mu*mu;
  const float rstd = rsqrtf(var+EPS_);
  float* orow = out + r*(long)D_;
  orow[tid]     = (v0-mu)*rstd*ldin(s, offS+tid, isbf)     + ldin(b, offB+tid, isbf);
  orow[tid+256] = (v1-mu)*rstd*ldin(s, offS+tid+256, isbf) + ldin(b, offB+tid+256, isbf);
}

// ---------------- causal conv(K=4) + silu ----------------
__global__ void conv_silu(const float* __restrict__ in, int inStride,
                          const void* __restrict__ w, long offW,
                          const void* __restrict__ bias, long offBias,
                          float* __restrict__ out, int Dc,
                          const int* __restrict__ dflag)
{
  const int isbf = *dflag;
  const long total = (long)BT_ * Dc;
  for (long idx = (long)blockIdx.x*256 + threadIdx.x; idx < total;
       idx += (long)gridDim.x*256) {
    const int d = (int)(idx % Dc);
    const long bt = idx / Dc;
    const int b = (int)(bt / T_), t = (int)(bt % T_);
    float a = ldin(bias, offBias + d, isbf);
#pragma unroll
    for (int kk = 0; kk < 4; kk++) {
      const int ts = t - 3 + kk;
      if (ts >= 0) a += ldin(w, offW + kk*Dc + d, isbf) * in[((long)(b*T_+ts))*inStride + d];
    }
    out[idx] = siluf(a);
  }
}

// ---------------- fallback SIMT GEMM ----------------
// flags: 1=bias, 2=accumulate, 4=gelu, 8=store bf16
__global__ __launch_bounds__(256) void gemm_f32b(
    const float* __restrict__ A, const void* __restrict__ Bw, long offB,
    const void* __restrict__ bias, long offBias, float* __restrict__ C,
    int M, int N, int K, int lda, int ldb, int ldc,
    long strideA, long strideB, long strideC, long strideBias,
    float alpha, int flags, const int* __restrict__ dflag)
{
  const int isbf = *dflag;
  const int bz = blockIdx.z;
  A  += (long)bz * strideA;
  const long bB = offB + (long)bz * strideB;
  const long cBase = (long)bz * strideC;
  const long bBias = offBias + (long)bz * strideBias;
  __shared__ float sA[16][68];
  __shared__ float sB[16][64];
  const int tid = threadIdx.x;
  const int tx = tid & 15, ty = tid >> 4;
  const int m0 = blockIdx.y * 64, n0 = blockIdx.x * 64;
  float acc[4][4];
#pragma unroll
  for (int i=0;i<4;i++)
#pragma unroll
    for (int j=0;j<4;j++) acc[i][j]=0.f;

  for (int k0 = 0; k0 < K; k0 += 16) {
#pragma unroll
    for (int r = 0; r < 4; r++) {
      int lin = tid + r*256;
      int kk = lin & 15, m = lin >> 4;
      int gm = m0 + m, gk = k0 + kk;
      sA[kk][m] = (gm < M && gk < K) ? A[(long)gm*lda + gk] : 0.f;
    }
#pragma unroll
    for (int r = 0; r < 4; r++) {
      int lin = tid + r*256;
      int nn = lin & 63, kk = lin >> 6;
      int gn = n0 + nn, gk = k0 + kk;
      sB[kk][nn] = (gn < N && gk < K) ? ldin(Bw, bB + (long)gk*ldb + gn, isbf) : 0.f;
    }
    __syncthreads();
#pragma unroll
    for (int kk = 0; kk < 16; kk++) {
      const float4 a4 = *(const float4*)(&sA[kk][ty*4]);
      const float4 b4 = *(const float4*)(&sB[kk][tx*4]);
      float av[4] = {a4.x, a4.y, a4.z, a4.w};
      float bv[4] = {b4.x, b4.y, b4.z, b4.w};
#pragma unroll
      for (int i=0;i<4;i++)
#pragma unroll
        for (int j=0;j<4;j++) acc[i][j] += av[i]*bv[j];
    }
    __syncthreads();
  }
#pragma unroll
  for (int i=0;i<4;i++) {
    const int gm = m0 + ty*4 + i;
    if (gm >= M) continue;
#pragma unroll
    for (int j=0;j<4;j++) {
      const int gn = n0 + tx*4 + j;
      if (gn >= N) continue;
      float vv = acc[i][j]*alpha;
      if (flags & 1) vv += ldin(bias, bBias + gn, isbf);
      if (flags & 4) vv = geluf(vv);
      const long idx = cBase + (long)gm*ldc + gn;
      if (flags & 8) {
        ((unsigned short*)C)[idx] = f2bu(vv);
      } else {
        if (flags & 2) vv += C[idx];
        C[idx] = vv;
      }
    }
  }
}

// ---------------- sLSTM recurrent scan: one block per (b, head) ----------------
__global__ __launch_bounds__(256) void slstm_scan(
    const float* __restrict__ g4, const void* __restrict__ Rg, long offR,
    float* __restrict__ hs, const int* __restrict__ dflag)
{
  const int isbf = *dflag;
  const int blk = blockIdx.x;
  const int b = blk >> 3, hd = blk & 7;
  const int tid = threadIdx.x;
  const int g = tid >> 6, e = tid & 63;
  float w[64];
  {
    const long wp = offR + ((long)(g*NH_ + hd)*64)*64 + e;
#pragma unroll
    for (int d = 0; d < 64; d++) w[d] = ldin(Rg, wp + d*64, isbf);
  }
  __shared__ float hlds[64];
  __shared__ float rec[4][64];
  if (tid < 64) hlds[tid] = 0.f;
  float c = 0.f, n = 0.f, m = 0.f;
  __syncthreads();
  const long gate_base = (long)(b*T_)*D_ + hd*64 + e;
  for (int t = 0; t < T_; t++) {
    float r = 0.f;
#pragma unroll
    for (int d4 = 0; d4 < 16; d4++) {
      const float4 hv = *(const float4*)(&hlds[d4*4]);
      r += w[4*d4]*hv.x + w[4*d4+1]*hv.y + w[4*d4+2]*hv.z + w[4*d4+3]*hv.w;
    }
    r += g4[(long)g*BT_*D_ + gate_base + (long)t*D_];
    rec[g][e] = r;
    __syncthreads();
    if (tid < 64) {
      const float it = rec[0][e], ft = rec[1][e];
      const float zt = tanhf(rec[2][e]);
      const float ot = 1.f/(1.f+expf(-rec[3][e]));
      const float mn = fmaxf(ft + m, it);
      const float ig = expf(it - mn);
      const float fg = expf(ft + m - mn);
      c = fg*c + ig*zt;
      n = fg*n + ig;
      m = mn;
      const float hn = ot*c/fmaxf(n, 1e-6f);
      hlds[e] = hn;
      hs[(long)(b*T_+t)*D_ + hd*64 + e] = hn;
    }
    __syncthreads();
  }
}

// ---------------- head_norm(dh=64) * gn, accumulated into h ----------------
__global__ __launch_bounds__(64) void hn_add(
    const float* __restrict__ hs, const void* __restrict__ gn, long offG,
    float* __restrict__ h, const int* __restrict__ dflag)
{
  const int isbf = *dflag;
  const int blk = blockIdx.x;
  const int bt = blk >> 3, hd = blk & 7;
  const int e = threadIdx.x;
  const long idx = (long)bt*D_ + hd*64 + e;
  const float x = hs[idx];
  float s1 = x, s2 = x*x;
#pragma unroll
  for (int o = 32; o > 0; o >>= 1) { s1 += __shfl_xor(s1, o); s2 += __shfl_xor(s2, o); }
  const float mu = s1*(1.f/64.f);
  const float var = s2*(1.f/64.f) - mu*mu;
  const float y = (x-mu)*rsqrtf(var+EPS_)*ldin(gn, offG + hd*64+e, isbf);
  h[idx] += y;
}

// ---------------- FF gating: gelu(g)*up, written with 704 stride (zero pad) ----------------
__global__ void ffgate(const float* __restrict__ u, float* __restrict__ out)
{
  const long total = (long)BT_*FFP_;
  for (long idx = (long)blockIdx.x*256 + threadIdx.x; idx < total;
       idx += (long)gridDim.x*256) {
    const long m = idx / FFP_;
    const int j = (int)(idx % FFP_);
    float r = 0.f;
    if (j < FF_) {
      const float g = u[m*FF2_ + j];
      r = geluf(g) * u[m*FF2_ + FF_ + j];
    }
    out[idx] = r;
  }
}

// ---------------- mLSTM gate cumsum: one block per (b, head) ----------------
__global__ __launch_bounds__(256) void mlstm_cf(
    const float* __restrict__ g16, float* __restrict__ cf, float* __restrict__ logi)
{
  const int bh = blockIdx.x;
  const int b = bh >> 3, hd = bh & 7;
  const int tid = threadIdx.x;
  __shared__ float slf[T_];
  if (tid < T_) {
    const float gf = g16[(long)(b*T_+tid)*16 + 8 + hd];
    const float ls = (gf >= 0.f) ? -log1pf(expf(-gf)) : (gf - log1pf(expf(gf)));
    slf[tid] = ls;
    logi[(long)bh*T_ + tid] = g16[(long)(b*T_+tid)*16 + hd];
  }
  __syncthreads();
  if (tid == 0) {
    float a = 0.f;
    for (int t = 0; t < T_; t++) { a += slf[t]; slf[t] = a; }
  }
  __syncthreads();
  if (tid < T_) cf[(long)bh*T_ + tid] = slf[tid];
}

// ---------------- MFMA flash attention ----------------
// grid (4 t-tiles, 256 bh); 4 waves, wave w owns Q rows [t0+w*16, t0+w*16+16)
#define QPD 136
#define VPD 72
__global__ __launch_bounds__(256) void attn_mfma(
    const float* __restrict__ q, const unsigned short* __restrict__ k,
    const unsigned short* __restrict__ v, const float* __restrict__ cf,
    const float* __restrict__ li, float* __restrict__ hatt)
{
  const int tt = blockIdx.x, bh = blockIdx.y;
  const int b = bh >> 3, hd = bh & 7;
  const int t0 = tt*64;
  const int tid = threadIdx.x;
  const int w = tid >> 6, lane = tid & 63;
  const int lr = lane & 15, lq = lane >> 4;

  __shared__ unsigned short sQ[64*QPD];   // Q bf16, row-major, 16B-mult rows
  __shared__ unsigned short sK[64*QPD];   // K bf16, row-major
  __shared__ unsigned short sVt[128*VPD]; // V^T bf16 [d][s]
  __shared__ unsigned short sS[64*VPD];   // P bf16 (C-layout -> A-layout roundtrip)
  __shared__ float scft[64], scfs[64], slis[64];

  // stage Q once (fp32 -> bf16 pairs)
  for (int idx = tid; idx < 64*64; idx += 256){
    int r = idx >> 6, dp = idx & 63;
    int t = t0 + r;
    unsigned pk = 0;
    if (t < T_){
      const float* qp = q + ((long)(b*T_+t))*DI_ + hd*DHI_ + dp*2;
      pk = packbf(qp[0], qp[1]);
    }
    *(unsigned*)&sQ[r*QPD + dp*2] = pk;
  }
  if (tid < 64) scft[tid] = (t0+tid < T_) ? cf[(long)bh*T_ + t0+tid] : 0.f;

  float m_st[4], s_st[4], alpha_[4];
#pragma unroll
  for (int rr=0;rr<4;rr++){ m_st[rr] = -INFINITY; s_st[rr] = 0.f; }
  floatx4 accO[8];
#pragma unroll
  for (int nd=0;nd<8;nd++)
#pragma unroll
    for (int rr=0;rr<4;rr++) accO[nd][rr] = 0.f;

  for (int st = 0; st <= tt; st++){
    const int s0 = st*64;
    // stage K row-major and V transposed
    for (int idx = tid; idx < 64*64; idx += 256){
      int r = idx >> 6, dp = idx & 63;
      int s = s0 + r;
      unsigned pkk = 0, pkv = 0;
      if (s < T_){
        const long base = ((long)(b*T_+s))*DI_ + hd*DHI_ + dp*2;
        pkk = *(const unsigned*)&k[base];
        pkv = *(const unsigned*)&v[base];
      }
      *(unsigned*)&sK[r*QPD + dp*2] = pkk;
      sVt[(dp*2)*VPD + r]   = (unsigned short)(pkv & 0xFFFFu);
      sVt[(dp*2+1)*VPD + r] = (unsigned short)(pkv >> 16);
    }
    if (tid < 64){
      int s = s0 + tid;
      scfs[tid] = (s < T_) ? cf[(long)bh*T_ + s] : 0.f;
      slis[tid] = (s < T_) ? li[(long)bh*T_ + s] : 0.f;
    }
    __syncthreads();

    // ---- S = Q K^T (wave strip 16 x 64) ----
    floatx4 accS[4];
#pragma unroll
    for (int ni=0;ni<4;ni++)
#pragma unroll
      for (int rr=0;rr<4;rr++) accS[ni][rr] = 0.f;
    const int qrow = w*16 + lr;
#pragma unroll
    for (int k0=0;k0<4;k0++){
      short8 a = *(const short8*)&sQ[qrow*QPD + k0*32 + lq*8];
#pragma unroll
      for (int ni=0;ni<4;ni++){
        short8 bb = *(const short8*)&sK[(ni*16+lr)*QPD + k0*32 + lq*8];
        accS[ni] = __builtin_amdgcn_mfma_f32_16x16x32_bf16(a, bb, accS[ni], 0,0,0);
      }
    }

    // ---- decay + online softmax (state in registers, row = lq*4+rr) ----
#pragma unroll
    for (int rr=0;rr<4;rr++){
      const int tg = t0 + w*16 + lq*4 + rr;
      const float cftr = scft[w*16 + lq*4 + rr];
      float dmv[4];
      float mx = -INFINITY;
#pragma unroll
      for (int ni=0;ni<4;ni++){
        const int sg = s0 + ni*16 + lr;
        const bool valid = (tg < T_) && (sg <= tg);
        dmv[ni] = valid ? (cftr - scfs[ni*16+lr] + slis[ni*16+lr]) : -INFINITY;
        mx = fmaxf(mx, dmv[ni]);
      }
      mx = fmaxf(mx, __shfl_xor(mx, 1));
      mx = fmaxf(mx, __shfl_xor(mx, 2));
      mx = fmaxf(mx, __shfl_xor(mx, 4));
      mx = fmaxf(mx, __shfl_xor(mx, 8));
      const float mnew = fmaxf(m_st[rr], mx);
      const float al = (mnew == -INFINITY) ? 0.f : expf(m_st[rr] - mnew);
      float rs = 0.f;
#pragma unroll
      for (int ni=0;ni<4;ni++){
        const float wexp = (dmv[ni] == -INFINITY) ? 0.f : expf(dmv[ni] - mnew);
        const float pv = accS[ni][rr]*wexp;
        rs += pv;
        sS[(w*16 + lq*4 + rr)*VPD + ni*16 + lr] = f2bu(pv);
      }
      rs += __shfl_xor(rs, 1);
      rs += __shfl_xor(rs, 2);
      rs += __shfl_xor(rs, 4);
      rs += __shfl_xor(rs, 8);
      s_st[rr] = s_st[rr]*al + rs;
      m_st[rr] = mnew;
      alpha_[rr] = al;
    }

    // rescale O by alpha (same row mapping as C layout)
#pragma unroll
    for (int nd=0;nd<8;nd++)
#pragma unroll
      for (int rr=0;rr<4;rr++) accO[nd][rr] *= alpha_[rr];

    // ---- O += P V  (P via LDS roundtrip into A-layout; V^T as B operand) ----
#pragma unroll
    for (int ks=0;ks<2;ks++){
      short8 aP = *(const short8*)&sS[(w*16 + lr)*VPD + ks*32 + lq*8];
#pragma unroll
      for (int nd=0;nd<8;nd++){
        short8 bV = *(const short8*)&sVt[(nd*16+lr)*VPD + ks*32 + lq*8];
        accO[nd] = __builtin_amdgcn_mfma_f32_16x16x32_bf16(aP, bV, accO[nd], 0,0,0);
      }
    }
    __syncthreads();
  }

  // ---- epilogue: h = O / max(|sum|, exp(-m)) ----
#pragma unroll
  for (int rr=0;rr<4;rr++){
    const int tg = t0 + w*16 + lq*4 + rr;
    if (tg >= T_) continue;
    const float inv = 1.f / fmaxf(fabsf(s_st[rr]), expf(-m_st[rr]));
    float* op = hatt + ((long)(b*T_+tg))*DI_ + hd*DHI_;
#pragma unroll
    for (int nd=0;nd<8;nd++)
      op[nd*16 + lr] = accO[nd][rr]*inv;
  }
}

// ---------------- head_norm(dh=128)*gn + skip*xc, then *silu(z) ----------------
__global__ __launch_bounds__(128) void hn_mlstm(
    const float* __restrict__ hatt, const void* __restrict__ gn, long offG,
    const void* __restrict__ skip, long offSk, const float* __restrict__ xc,
    const float* __restrict__ u, float* __restrict__ gin,
    const int* __restrict__ dflag)
{
  const int isbf = *dflag;
  const int blk = blockIdx.x;
  const int bt = blk >> 3, hd = blk & 7;
  const int e = threadIdx.x;
  const int j = hd*DHI_ + e;
  const long idx = (long)bt*DI_ + j;
  const float x = hatt[idx];
  __shared__ float r1[128], r2[128];
  r1[e]=x; r2[e]=x*x; __syncthreads();
  for (int o=64;o>0;o>>=1){ if(e<o){r1[e]+=r1[e+o]; r2[e]+=r2[e+o];} __syncthreads(); }
  const float mu = r1[0]*(1.f/128.f);
  const float var = r2[0]*(1.f/128.f)-mu*mu;
  const float y = (x-mu)*rsqrtf(var+EPS_)*ldin(gn, offG+j, isbf) + ldin(skip, offSk+j, isbf)*xc[idx];
  const float z = u[(long)bt*2048 + DI_ + j];
  gin[idx] = y * siluf(z);
}

// ---------------- final transpose to output ----------------
__global__ void out_transpose(const float* __restrict__ hp, void* __restrict__ out,
                              const int* __restrict__ dflag)
{
  const int isbf = *dflag;
  const int tid = threadIdx.x;
  if (tid < B_*6) {
    const int b = tid / 6, hd = tid % 6;
    const float v = hp[hd*B_ + b];
    if (isbf) ((bf16*)out)[tid] = __float2bfloat16(v);
    else      ((float*)out)[tid] = v;
  }
}

extern "C" void kernel_launch(void* const* d_in, const int* in_sizes, int n_in,
                              void* d_out, int out_size, void* d_ws, size_t ws_size,
                              hipStream_t stream)
{
  (void)in_sizes; (void)n_in; (void)out_size;
  const void* x        = d_in[0];
  const void* w_in     = d_in[1];
  const void* b_in     = d_in[2];
  const void* ln_in_s  = d_in[3];
  const void* ln_in_b  = d_in[4];
  const void* s_ln_s   = d_in[5];
  const void* s_ln_b   = d_in[6];
  const void* s_conv_w = d_in[7];
  const void* s_conv_b = d_in[8];
  const void* s_wg     = d_in[9];
  const void* s_rg     = d_in[10];
  const void* s_bg     = d_in[11];
  const void* s_gn     = d_in[12];
  const void* s_ffln_s = d_in[13];
  const void* s_ffln_b = d_in[14];
  const void* s_ff_w1  = d_in[15];
  const void* s_ff_w2  = d_in[16];
  const void* m_ln_s   = d_in[17];
  const void* m_ln_b   = d_in[18];
  const void* m_w_up   = d_in[19];
  const void* m_conv_w = d_in[20];
  const void* m_conv_b = d_in[21];
  const void* m_wq     = d_in[22];
  const void* m_wk     = d_in[23];
  const void* m_wv     = d_in[24];
  const void* m_w_if   = d_in[25];
  const void* m_b_if   = d_in[26];
  const void* m_skip   = d_in[27];
  const void* m_gn     = d_in[28];
  const void* m_w_down = d_in[29];
  const void* post_ln_s= d_in[30];
  const void* post_ln_b= d_in[31];
  const void* hw1      = d_in[32];
  const void* hb1      = d_in[33];
  const void* hw2      = d_in[34];
  const void* hb2      = d_in[35];
  const void* hw3      = d_in[36];
  const void* hb3      = d_in[37];

  float* W   = (float*)d_ws;
  float* h   = W;                           // BT*D
  float* xn  = W + 4128768L;                // BT*D
  float* xc  = W + 8257536L;                // BT*DI
  float* u   = W + 16515072L;               // 4*BT*D
  float* q   = W + 33030144L;               // BT*DI fp32 (hs / ffg(704) / hatt / gin)
  unsigned short* kk_ = (unsigned short*)(W + 41287680L); // BT*DI bf16
  unsigned short* vv_ = (unsigned short*)(W + 45416448L); // BT*DI bf16
  float* g16 = W + 49545216L;               // BT*16
  float* cfb = W + 49674240L;               // B*NH*T
  float* lib = W + 49738752L;               // B*NH*T
  float* last= W + 49803264L;               // 32*512
  float* ha1 = W + 49819648L;               // 6*32*256
  float* ha2 = W + 49868800L;               // 6*32*128
  float* hp  = W + 49893376L;               // 6*32 (pad)
  int*   dfl = (int*)(W + 49893568L);

  // bf16 weight planes (hi, lo), each PLANE ushorts, k-contiguous [N][K]
  const long PLANE = 14327808L;
  unsigned short* wtHi = (unsigned short*)(W + 49893632L);
  unsigned short* wtLo = wtHi + PLANE;
  const long oWg=0, oF1=4194304L, oF2=6987776L, oUp=8429568L;
  const long oQ=11575296L, oK=11968512L, oV=12361728L, oDn=12754944L;

  const size_t needFull = (size_t)49893632L*4 + (size_t)PLANE*4;  // ~257 MB
  const size_t needMid  = (size_t)49893632L*4 + (size_t)PLANE*2;  // ~228 MB
  const int tier = (ws_size >= needFull) ? 2 : ((ws_size >= needMid) ? 1 : 0);
  const int spB = (tier == 2) ? 1 : 0;
  unsigned short* loArg = (tier == 2) ? wtLo : nullptr;

  const float kscale = 0.08838834764831845f; // 1/sqrt(128)

  detect_dtype<<<1, 64, 0, stream>>>((const unsigned*)ln_in_s, dfl);

  if (tier >= 1) {
    wt_transpose2<<<dim3(16,16,16),256,0,stream>>>(s_wg, 0, 262144L, 512, 512, 512,
        wtHi+oWg, loArg?loArg+oWg:nullptr, 262144L, dfl);
    wt_transpose2<<<dim3(43,16,4),256,0,stream>>>(s_ff_w1, 0, 698368L, 512, 1364, 512,
        wtHi+oF1, loArg?loArg+oF1:nullptr, 698368L, dfl);
    wt_transpose2<<<dim3(16,22,4),256,0,stream>>>(s_ff_w2, 0, 349184L, 682, 512, 704,
        wtHi+oF2, loArg?loArg+oF2:nullptr, 360448L, dfl);
    wt_transpose2<<<dim3(64,16,3),256,0,stream>>>(m_w_up, 0, 1048576L, 512, 2048, 512,
        wtHi+oUp, loArg?loArg+oUp:nullptr, 1048576L, dfl);
    wt_transpose2<<<dim3(4,4,24),256,0,stream>>>(m_wq, 0, 16384L, 128, 128, 128,
        wtHi+oQ, loArg?loArg+oQ:nullptr, 16384L, dfl);
    wt_transpose2<<<dim3(4,4,24),256,0,stream>>>(m_wk, 0, 16384L, 128, 128, 128,
        wtHi+oK, loArg?loArg+oK:nullptr, 16384L, dfl);
    wt_transpose2<<<dim3(4,4,24),256,0,stream>>>(m_wv, 0, 16384L, 128, 128, 128,
        wtHi+oV, loArg?loArg+oV:nullptr, 16384L, dfl);
    wt_transpose2<<<dim3(16,32,3),256,0,stream>>>(m_w_down, 0, 524288L, 1024, 512, 1024,
        wtHi+oDn, loArg?loArg+oDn:nullptr, 524288L, dfl);
  }

  ln_proj<<<BT_, 256, 0, stream>>>(x, w_in, b_in, ln_in_s, ln_in_b, h, dfl);

  int si = 0, mi = 0;
  for (int blk = 0; blk < 7; blk++) {
    if ((blk & 1) == 0) {
      // ---- sLSTM block ----
      ln_rows<<<BT_,256,0,stream>>>(h, 512L, s_ln_s, (long)si*512, s_ln_b, (long)si*512, xn, dfl);
      {
        long tot = (long)BT_*512; int g = (int)((tot+255)/256);
        conv_silu<<<g,256,0,stream>>>(xn, 512, s_conv_w, (long)si*4*512, s_conv_b, (long)si*512, xc, 512, dfl);
      }
      if (tier >= 1) {
        gemm_split<<<dim3(8,126,4),256,0,stream>>>(xc, xn, 2, 0L,
            wtHi+oWg+(long)si*4*262144L, wtLo+oWg+(long)si*4*262144L,
            s_bg, (long)si*4*512, u,
            512, 512, 512, 512, 262144L, (long)BT_*512, 512L, 1.f, 1, spB, dfl);
      } else {
        for (int g = 0; g < 4; g++) {
          const float* Ain = (g < 2) ? xc : xn;
          gemm_f32b<<<dim3(8,126,1),256,0,stream>>>(Ain, s_wg, ((long)(si*4+g))*512*512,
              s_bg, (long)(si*4+g)*512, u + (long)g*BT_*512,
              BT_, 512, 512, 512, 512, 512, 0,0,0,0, 1.f, 1, dfl);
        }
      }
      slstm_scan<<<256,256,0,stream>>>(u, s_rg, (long)si*4*8*64*64, q /*hs*/, dfl);
      hn_add<<<BT_*8,64,0,stream>>>(q, s_gn, (long)si*512, h, dfl);
      // ---- FF block ----
      ln_rows<<<BT_,256,0,stream>>>(h, 512L, s_ffln_s, (long)si*512, s_ffln_b, (long)si*512, xn, dfl);
      if (tier >= 1)
        gemm_split<<<dim3(22,126,1),256,0,stream>>>(xn, xn, 9, 0L,
            wtHi+oF1+(long)si*698368L, wtLo+oF1+(long)si*698368L, nullptr, 0,
            u, 1364, 512, 512, 1364, 0,0,0, 1.f, 0, spB, dfl);
      else
        gemm_f32b<<<dim3(22,126,1),256,0,stream>>>(xn, s_ff_w1, (long)si*512*1364, nullptr, 0,
            u, BT_, 1364, 512, 512, 1364, 1364, 0,0,0,0, 1.f, 0, dfl);
      {
        long tot = (long)BT_*FFP_; int g = (int)((tot+255)/256);
        ffgate<<<g,256,0,stream>>>(u, q /*ffg, stride 704*/);
      }
      if (tier >= 1)
        gemm_split<<<dim3(8,126,1),256,0,stream>>>(q, q, 9, 0L,
            wtHi+oF2+(long)si*360448L, wtLo+oF2+(long)si*360448L, nullptr, 0,
            h, 512, 704, 704, 512, 0,0,0, 1.f, 2, spB, dfl);
      else
        gemm_f32b<<<dim3(8,126,1),256,0,stream>>>(q, s_ff_w2, (long)si*682*512, nullptr, 0,
            h, BT_, 512, 682, 704, 512, 512, 0,0,0,0, 1.f, 2, dfl);
      si++;
    } else {
      // ---- mLSTM block ----
      ln_rows<<<BT_,256,0,stream>>>(h, 512L, m_ln_s, (long)mi*512, m_ln_b, (long)mi*512, xn, dfl);
      if (tier >= 1)
        gemm_split<<<dim3(32,126,1),256,0,stream>>>(xn, xn, 9, 0L,
            wtHi+oUp+(long)mi*1048576L, wtLo+oUp+(long)mi*1048576L, nullptr, 0,
            u, 2048, 512, 512, 2048, 0,0,0, 1.f, 0, spB, dfl);
      else
        gemm_f32b<<<dim3(32,126,1),256,0,stream>>>(xn, m_w_up, (long)mi*512*2048, nullptr, 0,
            u, BT_, 2048, 512, 512, 2048, 2048, 0,0,0,0, 1.f, 0, dfl);
      {
        long tot = (long)BT_*1024; int g = (int)((tot+255)/256);
        conv_silu<<<g,256,0,stream>>>(u, 2048, m_conv_w, (long)mi*4*1024, m_conv_b, (long)mi*1024, xc, 1024, dfl);
      }
      if (tier >= 1) {
        gemm_split<<<dim3(2,126,8),256,0,stream>>>(xc, xc, 9, 128L,
            wtHi+oQ+(long)mi*131072L, wtLo+oQ+(long)mi*131072L, nullptr, 0,
            q, 128, 128, 1024, 1024, 16384L, 128L, 0, 1.f, 0, spB, dfl);
        gemm_split<<<dim3(2,126,8),256,0,stream>>>(xc, xc, 9, 128L,
            wtHi+oK+(long)mi*131072L, wtLo+oK+(long)mi*131072L, nullptr, 0,
            (float*)kk_, 128, 128, 1024, 1024, 16384L, 128L, 0, kscale, 8, spB, dfl);
        gemm_split<<<dim3(2,126,8),256,0,stream>>>(u, u, 9, 128L,
            wtHi+oV+(long)mi*131072L, wtLo+oV+(long)mi*131072L, nullptr, 0,
            (float*)vv_, 128, 128, 2048, 1024, 16384L, 128L, 0, 1.f, 8, spB, dfl);
      } else {
        gemm_f32b<<<dim3(2,126,8),256,0,stream>>>(xc, m_wq, (long)mi*8*128*128, nullptr, 0,
            q, BT_, 128, 128, 1024, 128, 1024, 128, 16384, 128, 0, 1.f, 0, dfl);
        gemm_f32b<<<dim3(2,126,8),256,0,stream>>>(xc, m_wk, (long)mi*8*128*128, nullptr, 0,
            (float*)kk_, BT_, 128, 128, 1024, 128, 1024, 128, 16384, 128, 0, kscale, 8, dfl);
        gemm_f32b<<<dim3(2,126,8),256,0,stream>>>(u, m_wv, (long)mi*8*128*128, nullptr, 0,
            (float*)vv_, BT_, 128, 128, 2048, 128, 1024, 128, 16384, 128, 0, 1.f, 8, dfl);
      }
      gemm_f32b<<<dim3(1,126,1),256,0,stream>>>(xc, m_w_if, (long)mi*1024*16, m_b_if, (long)mi*16,
            g16, BT_, 16, 1024, 1024, 16, 16, 0,0,0,0, 1.f, 1, dfl);
      mlstm_cf<<<256,256,0,stream>>>(g16, cfb, lib);
      attn_mfma<<<dim3(4,256),256,0,stream>>>(q, kk_, vv_, cfb, lib, q /*hatt in-place*/);
      hn_mlstm<<<BT_*8,128,0,stream>>>(q, m_gn, (long)mi*1024, m_skip, (long)mi*1024, xc, u, q, dfl);
      if (tier >= 1)
        gemm_split<<<dim3(8,126,1),256,0,stream>>>(q, q, 9, 0L,
            wtHi+oDn+(long)mi*524288L, wtLo+oDn+(long)mi*524288L, nullptr, 0,
            h, 512, 1024, 1024, 512, 0,0,0, 1.f, 2, spB, dfl);
      else
        gemm_f32b<<<dim3(8,126,1),256,0,stream>>>(q, m_w_down, (long)mi*1024*512, nullptr, 0,
            h, BT_, 512, 1024, 1024, 512, 512, 0,0,0,0, 1.f, 2, dfl);
      mi++;
    }
  }

  // post-LN on last timestep rows only
  ln_rows<<<B_,256,0,stream>>>(h + (long)(T_-1)*512, (long)T_*512, post_ln_s, 0, post_ln_b, 0, last, dfl);

  // 6 prediction heads, batched over grid.z (tiny; SIMT fp32)
  gemm_f32b<<<dim3(4,1,6),256,0,stream>>>(last, hw1, 0, hb1, 0, ha1, 32, 256, 512, 512, 256, 256,
        0, 512L*256, 32L*256, 256, 1.f, 1|4, dfl);
  gemm_f32b<<<dim3(2,1,6),256,0,stream>>>(ha1, hw2, 0, hb2, 0, ha2, 32, 128, 256, 256, 128, 128,
        32L*256, 256L*128, 32L*128, 128, 1.f, 1|4, dfl);
  gemm_f32b<<<dim3(1,1,6),256,0,stream>>>(ha2, hw3, 0, hb3, 0, hp, 32, 1, 128, 128, 1, 1,
        32L*128, 128L, 32L, 1, 1.f, 1, dfl);
  out_transpose<<<1,256,0,stream>>>(hp, d_out, dfl);
}